// Round 4
// baseline (327.732 us; speedup 1.0000x reference)
//
#include <hip/hip_runtime.h>
#include <stdint.h>

#define BATCH 16
#define NROW 25200
#define NCLS 80
#define ROWF 85
#define MAXDET 300
#define MAXNMS 30000u
#define NBIN 3072
#define BASEBITS 0x3EC00000u
#define CAP 32768u
#define BATCH_FLOATS 2142000   // 25200*85

#define PREBIN 2048            // score >= 0.75
#define NBUCK 1024             // NBIN - PREBIN
#define CANDCAP 131072u
#define TOPK 2048u             // target size of the pre-ordered head
#define K2CAP 4096u            // TOPK + max bin (1024) + slack

#define SORTCAP 1024
#define CH_SZ 128

// fallback tiling (k_hist_fb / k_scatter_fb)
#define TILE_ROWS 80
#define TILE_FLOATS 6800
#define RPB 400
#define SUBT 5
#define SBLK 63

// k_stage geometry: 70 blocks/batch x 360 rows; per-wave private 12-row chunks
// (12*85 = 1020 floats = 255 f4 -> chunk bases stay 16B-aligned; DMA 4x64 f4,
// last f4 is a clamped over-read into the buffer pad slot)
#define SBLK2 70
#define RPB2 360
#define CH2 30                 // 12-row chunks per block
#define CH_F4 255u             // f4 per chunk
#define BLK2_F4 7650u          // RPB2*85/4
#define B_F4 535500u           // BATCH_FLOATS/4
#define TOTAL_F4 8568000u      // BATCH*B_F4
#define KMAXS 1536u            // per-block candidate cap (avg ~985 @360 rows, max+3.5sig ~1093)

// exact: fl(inter/den) > 0.5, division only at the rounding boundary
__device__ __forceinline__ bool iou_gt_half(float ax1, float ay1, float ax2, float ay2, float aa,
                                            float bx1, float by1, float bx2, float by2, float ba) {
    float ltx = fmaxf(ax1, bx1), lty = fmaxf(ay1, by1);
    float rbx = fminf(ax2, bx2), rby = fminf(ay2, by2);
    float wx = fmaxf(__fsub_rn(rbx, ltx), 0.0f);
    float wy = fmaxf(__fsub_rn(rby, lty), 0.0f);
    float inter = __fmul_rn(wx, wy);
    float den = __fadd_rn(__fsub_rn(__fadd_rn(aa, ba), inter), 1e-9f);
    float t = __fmul_rn(0.5f, den);
    if (!(inter > t)) return false;
    float tg = __fmul_rn(0.50000012f, den);
    if (inter >= tg) return true;
    return __fdiv_rn(inter, den) > 0.5f;
}

__device__ __forceinline__ unsigned bin_of_bits(unsigned bits) {
    unsigned v = (bits - BASEBITS) >> 12;
    if (v > (unsigned)(NBIN - 1)) v = NBIN - 1;
    return v;
}

// async global->LDS DMA: 16B per lane, LDS dest = wave-uniform base + lane*16
__device__ __forceinline__ void gload_lds16(const float4* g, float* lds_base_wave_uniform) {
    __builtin_amdgcn_global_load_lds((const __attribute__((address_space(1))) void*)g,
                                     (__attribute__((address_space(3))) void*)lds_base_wave_uniform,
                                     16, 0, 0);
}

// issue one 12-row chunk (255 f4 + 1 pad f4) into this wave's private buffer
__device__ __forceinline__ void issue_chunk(const float4* __restrict__ predf4,
                                            float* wbuf, unsigned chunk_f4_base, int lane) {
    #pragma unroll
    for (int j = 0; j < 4; ++j) {
        unsigned gi = chunk_f4_base + (unsigned)(j << 6) + (unsigned)lane;
        if (gi > TOTAL_F4 - 1u) gi = TOTAL_F4 - 1u;   // tail clamp (incl. pad f4)
        gload_lds16(predf4 + gi, wbuf + (size_t)(j << 8));   // j*64 f4 = j*256 floats
    }
}

// ---------------- K1: barrier-free per-wave streaming filter -------------------------
// Each wave owns a private double-buffered LDS region and its own 12-row chunks.
// vmcnt is per-wave, so s_waitcnt vmcnt(0) self-syncs each wave's DMA without any
// __syncthreads in the main loop -> no block-wide barrier drain, waves drift freely
// (round-3's barrier-per-subtile version measured ~2.1 TB/s effective; HBM floor 22us).
__global__ __launch_bounds__(512) void k_stage(const float* __restrict__ pred,
                                               unsigned* __restrict__ hist2,
                                               unsigned* __restrict__ ccnt,
                                               unsigned long long* __restrict__ cand,
                                               unsigned* __restrict__ oflow,
                                               int staged) {
    if (!staged) return;
    __shared__ __align__(16) float rows[8 * 2 * 1024];   // 8 waves x 2 bufs x 256 f4 = 64 KB
    __shared__ unsigned shist32[NBUCK / 2];              // 2 x u16 packed per word (2 KB)
    __shared__ unsigned long long skey[KMAXS];           // 12 KB
    __shared__ unsigned s_cnt, s_n, s_base;
    int bx = blockIdx.x;
    int b = bx / SBLK2, blk = bx - b * SBLK2;
    int t = threadIdx.x, lane = t & 63, wv = t >> 6;
    if (t < NBUCK / 2) shist32[t] = 0u;
    if (t == 0) s_cnt = 0u;

    const float4* predf4 = (const float4*)pred;
    unsigned tb0 = (unsigned)b * B_F4 + (unsigned)blk * BLK2_F4;
    int rowbase = blk * RPB2;
    float* wbase = rows + (wv << 11);          // wave's 2048-float (2x256 f4) region

    // prologue: this wave's first chunk -> buf0
    issue_chunk(predf4, wbase, tb0 + (unsigned)wv * CH_F4, lane);
    __syncthreads();   // publishes shist zero-init; drains prologue DMA (vmcnt0 per wave)

    int buf = 0;
    for (int c = wv; c < CH2; c += 8) {
        int nc = c + 8;
        if (nc < CH2)
            issue_chunk(predf4, wbase + ((buf ^ 1) << 10), tb0 + (unsigned)nc * CH_F4, lane);

        const float* rb = wbase + (buf << 10);
        int growbase = rowbase + c * 12;
        for (int r = 0; r < 12; ++r) {
            float obj = rb[r * ROWF + 4];
            bool live = (obj > 0.4f);          // wave-uniform (broadcast LDS read)
            if (live) {
                unsigned grow = (unsigned)(growbase + r);
                // segment 0: cols 0..63
                float s0 = __fmul_rn(rb[r * ROWF + 5 + lane], obj);   // exact op order
                bool h0 = (s0 >= 0.75f);
                unsigned long long m0 = __ballot(h0);
                if (m0) {
                    unsigned base0 = 0;
                    int lead = (int)__builtin_ctzll(m0);
                    if (lane == lead) base0 = atomicAdd(&s_cnt, (unsigned)__popcll(m0));
                    base0 = (unsigned)__shfl((int)base0, lead);
                    if (h0) {
                        unsigned bits = __float_as_uint(s0);
                        unsigned bin = bin_of_bits(bits) - PREBIN;
                        atomicAdd(&shist32[bin >> 1], 1u << ((bin & 1) << 4));
                        unsigned u = base0 + (unsigned)__popcll(m0 & ((1ULL << lane) - 1ULL));
                        unsigned flat = grow * (unsigned)NCLS + (unsigned)lane;
                        if (u < KMAXS)
                            skey[u] = ((unsigned long long)bits << 32) |
                                      (unsigned long long)(0xFFFFFFFFu - flat);
                        else oflow[b] = 1u;
                    }
                }
                // segment 1: cols 64..79 (lanes 0..15)
                bool h1 = false; float s1 = 0.0f;
                if (lane < 16) {
                    s1 = __fmul_rn(rb[r * ROWF + 69 + lane], obj);
                    h1 = (s1 >= 0.75f);
                }
                unsigned long long m1 = __ballot(h1);
                if (m1) {
                    unsigned base1 = 0;
                    int lead = (int)__builtin_ctzll(m1);
                    if (lane == lead) base1 = atomicAdd(&s_cnt, (unsigned)__popcll(m1));
                    base1 = (unsigned)__shfl((int)base1, lead);
                    if (h1) {
                        unsigned bits = __float_as_uint(s1);
                        unsigned bin = bin_of_bits(bits) - PREBIN;
                        atomicAdd(&shist32[bin >> 1], 1u << ((bin & 1) << 4));
                        unsigned u = base1 + (unsigned)__popcll(m1 & ((1ULL << lane) - 1ULL));
                        unsigned flat = grow * (unsigned)NCLS + (unsigned)(64 + lane);
                        if (u < KMAXS)
                            skey[u] = ((unsigned long long)bits << 32) |
                                      (unsigned long long)(0xFFFFFFFFu - flat);
                        else oflow[b] = 1u;
                    }
                }
            }
        }
        if (nc < CH2) {
            asm volatile("s_waitcnt vmcnt(0)" ::: "memory");   // own next-chunk DMA done
        }
        buf ^= 1;
    }

    __syncthreads();   // all waves done producing shist/skey/s_cnt

    // flush block-local hist (unpack 2xu16) + candidate buffer (unchanged semantics)
    unsigned* gh = hist2 + (size_t)b * NBUCK;
    if (t < NBUCK / 2) {
        unsigned w = shist32[t];
        unsigned lo = w & 0xFFFFu, hi = w >> 16;
        if (lo) atomicAdd(&gh[2 * t], lo);
        if (hi) atomicAdd(&gh[2 * t + 1], hi);
    }
    if (t == 0) {
        unsigned n = s_cnt;
        if (n > KMAXS) n = KMAXS;
        unsigned base = atomicAdd(&ccnt[b], n);
        if (base + n > CANDCAP) oflow[b] = 1u;
        s_n = n; s_base = base;
    }
    __syncthreads();
    unsigned n = s_n, base = s_base;
    if (base + n <= CANDCAP) {
        unsigned long long* cd = cand + (size_t)b * CANDCAP + base;
        for (unsigned k = t; k < n; k += 512) cd[k] = skey[k];
    }
}

// ---------------- K2: scan hist -> meta + suf2, scatter top-TOPK into keys2 ----------
__global__ __launch_bounds__(1024) void k_prep(const unsigned* __restrict__ hist2,
                                               const unsigned* __restrict__ ccnt,
                                               const unsigned* __restrict__ oflow,
                                               const unsigned long long* __restrict__ cand,
                                               unsigned* __restrict__ suf2,
                                               unsigned long long* __restrict__ keys2,
                                               int* __restrict__ meta,
                                               int staged) {
    __shared__ unsigned sS[NBUCK];
    __shared__ unsigned scur[NBUCK];
    __shared__ int s_cut, s_need, s_tot, s_T, s_valid;
    __shared__ unsigned s_bad, s_E;
    int b = blockIdx.x, t = threadIdx.x;   // 1024 threads == NBUCK
    unsigned h = hist2[(size_t)b * NBUCK + t];
    sS[t] = h;
    if (t == 0) { s_cut = -1; s_T = -1; s_bad = 0u; s_need = 0; s_tot = 0; s_E = 0u; }
    __syncthreads();
    if (h > (unsigned)SORTCAP) atomicOr(&s_bad, 1u);
    for (int off = 1; off < NBUCK; off <<= 1) {
        unsigned v = (t + off < NBUCK) ? sS[t + off] : 0u;
        __syncthreads();
        sS[t] += v;
        __syncthreads();
    }
    unsigned Sv = sS[t];
    unsigned Sn = (t + 1 < NBUCK) ? sS[t + 1] : 0u;
    if (Sv >= MAXNMS && Sn < MAXNMS) {
        s_cut = PREBIN + t; s_need = (int)(MAXNMS - Sn); s_tot = (int)Sv;
    }
    if (Sv >= TOPK && Sn < TOPK) { s_T = PREBIN + t; s_E = Sv; }
    unsigned* g2 = suf2 + (size_t)b * (NBUCK + 1);
    g2[t] = Sv;
    if (t == 0) g2[NBUCK] = 0u;
    scur[t] = Sn;                      // scatter base for bin PREBIN+t = S(v+1)
    __syncthreads();
    if (t == 0) {
        int valid = (staged && s_cut >= 0 && s_T >= 0 && s_bad == 0u &&
                     oflow[b] == 0u && ccnt[b] <= CANDCAP) ? 1 : 0;
        s_valid = valid;
        meta[b * 8 + 0] = valid ? s_cut : 0;
        meta[b * 8 + 1] = valid ? s_need : 0;
        meta[b * 8 + 2] = valid ? s_tot : 0;
        meta[b * 8 + 3] = valid;
        meta[b * 8 + 4] = valid ? s_T : 0;
        meta[b * 8 + 5] = valid ? (int)s_E : 0;
    }
    __syncthreads();
    if (s_valid) {
        int T = s_T;
        unsigned ccb = ccnt[b];
        const unsigned long long* cd = cand + (size_t)b * CANDCAP;
        unsigned long long* k2 = keys2 + (size_t)b * K2CAP;
        for (unsigned k = t; k < ccb; k += 1024) {
            unsigned long long key = cd[k];
            unsigned v = bin_of_bits((unsigned)(key >> 32));
            if ((int)v >= T) {
                unsigned pos = atomicAdd(&scur[v - PREBIN], 1u);
                if (pos < K2CAP) k2[pos] = key;
            }
        }
    }
}

// ---------------- K3a (fallback): full histogram ------------------------------------
__global__ __launch_bounds__(256) void k_hist_fb(const float* __restrict__ pred,
                                                 unsigned* __restrict__ hist,
                                                 const int* __restrict__ meta) {
    int bx = blockIdx.x;
    int b = bx / SBLK, blk = bx - b * SBLK;
    if (meta[b * 8 + 3]) return;
    __shared__ __align__(16) float rows[TILE_FLOATS];
    __shared__ unsigned shist[NBIN];
    int t = threadIdx.x, lane = t & 63, wv = t >> 6;
    for (int i = t; i < NBIN; i += 256) shist[i] = 0u;
    const float* pbase = pred + (size_t)b * BATCH_FLOATS + (size_t)blk * RPB * ROWF;
    for (int st = 0; st < SUBT; ++st) {
        __syncthreads();
        const float4* src = (const float4*)(pbase + (size_t)st * TILE_ROWS * ROWF);
        float4* dst = (float4*)rows;
        for (int i = t; i < TILE_FLOATS / 4; i += 256) dst[i] = src[i];
        __syncthreads();
        for (int r = wv; r < TILE_ROWS; r += 4) {
            float obj = rows[r * ROWF + 4];
            if (!(obj > 0.4f)) continue;
            for (int half = 0; half < 2; ++half) {
                int c = lane + (half << 6);
                if (c < NCLS) {
                    float s = __fmul_rn(rows[r * ROWF + 5 + c], obj);
                    if (s > 0.4f) atomicAdd(&shist[bin_of_bits(__float_as_uint(s))], 1u);
                }
            }
        }
    }
    __syncthreads();
    unsigned* gh = hist + (size_t)b * NBIN;
    for (int i = t; i < NBIN; i += 256) {
        unsigned v = shist[i];
        if (v) atomicAdd(&gh[i], v);
    }
}

// ---------------- K3b (fallback): suffix-scan full hist -> meta + suf ----------------
__global__ __launch_bounds__(256) void k_scan_fb(const unsigned* __restrict__ hist,
                                                 unsigned* __restrict__ suf,
                                                 int* __restrict__ meta) {
    int b = blockIdx.x, t = threadIdx.x;
    if (meta[b * 8 + 3]) return;
    __shared__ unsigned sh[NBIN];
    __shared__ unsigned sS[NBIN];
    __shared__ unsigned cs[256];
    __shared__ int s_cut, s_need, s_tot;
    const unsigned* gh = hist + (size_t)b * NBIN;
    for (int i = t; i < NBIN; i += 256) sh[i] = gh[i];
    if (t == 0) { s_cut = 0; s_need = 0x7FFFFFFF; s_tot = 0; }
    __syncthreads();
    const int CHUNK = NBIN / 256;
    int base = t * CHUNK;
    unsigned tot = 0;
    for (int i = 0; i < CHUNK; ++i) tot += sh[base + i];
    cs[t] = tot;
    __syncthreads();
    for (int off = 1; off < 256; off <<= 1) {
        unsigned v = (t + off < 256) ? cs[t + off] : 0u;
        __syncthreads();
        cs[t] += v;
        __syncthreads();
    }
    unsigned after = (t + 1 < 256) ? cs[t + 1] : 0u;
    for (int i = CHUNK - 1; i >= 0; --i) {
        after += sh[base + i];
        sS[base + i] = after;
    }
    __syncthreads();
    unsigned* gs = suf + (size_t)b * (NBIN + 1);
    for (int i = t; i < NBIN; i += 256) gs[i] = sS[i];
    if (t == 0) gs[NBIN] = 0u;
    for (int i = 0; i < CHUNK; ++i) {
        int v = base + i;
        unsigned Sv = sS[v];
        unsigned Sn = (v + 1 < NBIN) ? sS[v + 1] : 0u;
        if (Sv >= MAXNMS && Sn < MAXNMS) {
            s_cut = v; s_need = (int)(MAXNMS - Sn); s_tot = (int)Sv;
        }
    }
    __syncthreads();
    if (t == 0) {
        int cut = s_cut, needv = s_need, totv = s_tot;
        if (sS[0] < MAXNMS) { cut = 0; needv = 0x7FFFFFFF; totv = (int)sS[0]; }
        meta[b * 8 + 0] = cut;
        meta[b * 8 + 1] = needv;
        meta[b * 8 + 2] = totv;
    }
}

// ---------------- K3c (fallback): full re-read counting-scatter ----------------------
__global__ __launch_bounds__(256) void k_scatter_fb(const float* __restrict__ pred,
                                                    const unsigned* __restrict__ suf,
                                                    const int* __restrict__ meta,
                                                    unsigned* __restrict__ cursor,
                                                    unsigned long long* __restrict__ keys) {
    int bx = blockIdx.x;
    int b = bx / SBLK, blk = bx - b * SBLK;
    if (meta[b * 8 + 3]) return;
    __shared__ __align__(16) float rows[TILE_FLOATS];
    int t = threadIdx.x, lane = t & 63, wv = t >> 6;
    int cutbin = meta[b * 8 + 0];
    const float* pbase = pred + (size_t)b * BATCH_FLOATS + (size_t)blk * RPB * ROWF;
    unsigned rowbase0 = (unsigned)(blk * RPB);
    const unsigned* gs = suf + (size_t)b * (NBIN + 1);
    unsigned* cur = cursor + (size_t)b * NBIN;
    unsigned long long* kb = keys + (size_t)b * CAP;
    for (int st = 0; st < SUBT; ++st) {
        __syncthreads();
        const float4* src = (const float4*)(pbase + (size_t)st * TILE_ROWS * ROWF);
        float4* dst = (float4*)rows;
        for (int i = t; i < TILE_FLOATS / 4; i += 256) dst[i] = src[i];
        __syncthreads();
        for (int r = wv; r < TILE_ROWS; r += 4) {
            float obj = rows[r * ROWF + 4];
            if (!(obj > 0.4f)) continue;
            unsigned grow = rowbase0 + (unsigned)(st * TILE_ROWS + r);
            for (int half = 0; half < 2; ++half) {
                int c = lane + (half << 6);
                if (c < NCLS) {
                    float s = __fmul_rn(rows[r * ROWF + 5 + c], obj);
                    if (s > 0.4f) {
                        unsigned bits = __float_as_uint(s);
                        unsigned bin = bin_of_bits(bits);
                        if ((int)bin >= cutbin) {
                            unsigned pos = gs[bin + 1] + atomicAdd(&cur[bin], 1u);
                            if (pos < CAP) {
                                unsigned flat = grow * (unsigned)NCLS + (unsigned)c;
                                kb[pos] = ((unsigned long long)bits << 32) |
                                          (unsigned long long)(0xFFFFFFFFu - flat);
                            }
                        }
                    }
                }
            }
        }
    }
}

// ---------------- K4: NMS — contiguous keys2 gather, in-bin rank, 128-chunk mask -----
__global__ __launch_bounds__(1024) void k_nms(const float* __restrict__ pred,
                                              const unsigned* __restrict__ suf,
                                              const unsigned* __restrict__ suf2,
                                              const int* __restrict__ meta,
                                              const unsigned* __restrict__ ccnt,
                                              const unsigned long long* __restrict__ keys,
                                              const unsigned long long* __restrict__ keys2,
                                              const unsigned long long* __restrict__ cand,
                                              float* __restrict__ out) {
    __shared__ unsigned sgsL[NBUCK + 1];
    __shared__ unsigned long long ktmp[SORTCAP];
    __shared__ unsigned long long skeys[SORTCAP];
    __shared__ unsigned maskW[CH_SZ][5];
    __shared__ unsigned sup0w[4];
    __shared__ float cbox[CH_SZ][9];
    __shared__ float kept[MAXDET][5];
    __shared__ int klist[MAXDET];
    __shared__ int s_nk, s_localk;
    __shared__ unsigned s_gc;

    int b = blockIdx.x;
    int tid = threadIdx.x;
    int lane = tid & 63, wv = tid >> 6;

    int cutbin = meta[b * 8 + 0];
    int needv  = meta[b * 8 + 1];
    unsigned total = (unsigned)meta[b * 8 + 2];
    int valid  = meta[b * 8 + 3];
    int Tbin   = meta[b * 8 + 4];
    unsigned E = valid ? (unsigned)meta[b * 8 + 5] : 0u;
    if (!valid && total > CAP) total = CAP;
    const unsigned* gs = suf + (size_t)b * (NBIN + 1);
    const unsigned* g2 = suf2 + (size_t)b * (NBUCK + 1);
    const unsigned long long* kb = keys + (size_t)b * CAP;
    const unsigned long long* k2 = keys2 + (size_t)b * K2CAP;
    const unsigned long long* cd = cand + (size_t)b * CANDCAP;
    unsigned ccb = valid ? ccnt[b] : 0u;
    if (ccb > CANDCAP) ccb = CANDCAP;
    const float* pb = pred + (size_t)b * BATCH_FLOATS;
    float* ob = out + (size_t)b * MAXDET * 6;

    if (valid) for (int i = tid; i < NBUCK + 1; i += 1024) sgsL[i] = g2[i];
    if (tid == 0) s_nk = 0;
    __syncthreads();

#define GSV(v) (valid ? sgsL[(v) - PREBIN] : gs[(v)])

    unsigned limit;
    if (needv == 0x7FFFFFFF) limit = total;
    else limit = GSV(cutbin + 1) + (unsigned)needv;
    if (limit > total) limit = total;

    unsigned p = 0;
    while (p < limit) {
        if (s_nk >= MAXDET) break;

        // vs = smallest v with GSV(v) <= p + SORTCAP  -> maximal whole-bin extent
        int lo = cutbin, hi = NBIN - 1, vs = NBIN - 1;
        while (lo <= hi) { int mid = (lo + hi) >> 1;
            if (GSV(mid) <= p + (unsigned)SORTCAP) { vs = mid; hi = mid - 1; } else lo = mid + 1; }
        unsigned gEnd = GSV(vs);
        bool phaseA = (!valid) || (p < E);
        if (valid && phaseA && gEnd > E) gEnd = E;
        if (gEnd > total) gEnd = total;
        if (gEnd <= p) { gEnd = p + (unsigned)SORTCAP; if (gEnd > total) gEnd = total; }  // defensive
        unsigned G = gEnd - p;

        if (phaseA) {
            // dense bin-partitioned source indexed by absolute rank
            const unsigned long long* src = valid ? k2 : kb;
            unsigned myLo = 0, myHi = 0;
            unsigned long long raw = 0ULL;
            if (tid < (int)G) {
                unsigned idx = p + (unsigned)tid;
                int l2 = cutbin, h2 = NBIN - 1, v = cutbin;
                while (l2 <= h2) { int mid = (l2 + h2) >> 1;
                    if (GSV(mid) > idx) { v = mid; l2 = mid + 1; } else h2 = mid - 1; }
                unsigned bstart = GSV(v + 1);
                unsigned bend = GSV(v);
                raw = src[idx];
                myLo = (bstart > p) ? (bstart - p) : 0u;
                myHi = bend - p; if (myHi > G) myHi = G;
                ktmp[tid] = raw;
            }
            __syncthreads();
            if (tid < (int)G) {
                unsigned rank = 0;
                for (unsigned u = myLo; u < myHi; ++u) rank += (ktmp[u] > raw) ? 1u : 0u;
                skeys[myLo + rank] = raw;
            }
            __syncthreads();
        } else {
            // phase B (rare): filter-scan dense array for bins [vs, w1]
            int l0 = cutbin, h0 = NBIN - 1, w1 = cutbin;
            while (l0 <= h0) { int mid = (l0 + h0) >> 1;
                if (GSV(mid) > p) { w1 = mid; l0 = mid + 1; } else h0 = mid - 1; }
            if (tid == 0) s_gc = 0u;
            __syncthreads();
            for (unsigned k = tid; k < ccb; k += 1024) {
                unsigned long long key = cd[k];
                unsigned v = bin_of_bits((unsigned)(key >> 32));
                if ((int)v >= vs && (int)v <= w1) {
                    unsigned u = atomicAdd(&s_gc, 1u);
                    if (u < (unsigned)SORTCAP) ktmp[u] = key;
                }
            }
            __syncthreads();
            unsigned Gc = s_gc; if (Gc > (unsigned)SORTCAP) Gc = (unsigned)SORTCAP;
            if (tid < (int)Gc) {
                unsigned long long key = ktmp[tid];
                unsigned v = bin_of_bits((unsigned)(key >> 32));
                unsigned bstart = GSV(v + 1);
                unsigned rank = 0;
                for (unsigned u = 0; u < Gc; ++u) {
                    unsigned long long kk = ktmp[u];
                    unsigned vu = bin_of_bits((unsigned)(kk >> 32));
                    rank += (vu == v && kk > key) ? 1u : 0u;
                }
                skeys[(bstart - p) + rank] = key;
            }
            __syncthreads();
        }

        unsigned consumable = limit - p; if (consumable > G) consumable = G;

        for (unsigned c0 = 0; c0 < consumable; c0 += CH_SZ) {
            int nk0 = s_nk;
            if (nk0 >= MAXDET) break;
            int CH = (int)((consumable - c0 < (unsigned)CH_SZ) ? (consumable - c0) : (unsigned)CH_SZ);

            if (tid < CH_SZ * 5) maskW[tid / 5][tid % 5] = 0u;
            if (tid >= CH_SZ * 5 && tid < CH_SZ * 5 + 4) sup0w[tid - CH_SZ * 5] = 0u;
            if (tid < CH) {
                unsigned long long kk = skeys[c0 + tid];
                unsigned flat = 0xFFFFFFFFu - (unsigned)kk;
                unsigned bi = flat / (unsigned)NCLS;
                unsigned cc = flat - bi * (unsigned)NCLS;
                const float* rp = pb + (size_t)bi * ROWF;
                float cx = rp[0], cy = rp[1], wd = rp[2], ht = rp[3];
                float hw = __fmul_rn(0.5f, wd), hh = __fmul_rn(0.5f, ht);
                float off = __fmul_rn((float)cc, 4096.0f);
                float x1 = __fsub_rn(cx, hw), y1 = __fsub_rn(cy, hh);
                float x2 = __fadd_rn(cx, hw), y2 = __fadd_rn(cy, hh);
                float ox1 = __fadd_rn(x1, off), oy1 = __fadd_rn(y1, off);
                float ox2 = __fadd_rn(x2, off), oy2 = __fadd_rn(y2, off);
                cbox[tid][0] = ox1; cbox[tid][1] = oy1;
                cbox[tid][2] = ox2; cbox[tid][3] = oy2;
                cbox[tid][4] = __fmul_rn(__fsub_rn(ox2, ox1), __fsub_rn(oy2, oy1));
            }
            __syncthreads();

            {
                int col = tid & (CH_SZ - 1);
                int part = tid >> 7;
                if (col < CH) {
                    float bx1 = cbox[col][0], by1 = cbox[col][1];
                    float bx2 = cbox[col][2], by2 = cbox[col][3], ba = cbox[col][4];
                    unsigned part16 = 0u;
                    int rbase = part << 4;
                    for (int k = 0; k < 16; ++k) {
                        int i2 = rbase + k;
                        if (i2 >= col || i2 >= CH) break;
                        if (iou_gt_half(cbox[i2][0], cbox[i2][1], cbox[i2][2], cbox[i2][3],
                                        cbox[i2][4], bx1, by1, bx2, by2, ba))
                            part16 |= (1u << k);
                    }
                    if (part16)
                        atomicOr(&maskW[col][part >> 1], part16 << ((part & 1) << 4));
                    bool f = false;
                    for (int k2 = part; k2 < nk0; k2 += 8) {
                        if (iou_gt_half(kept[k2][0], kept[k2][1], kept[k2][2], kept[k2][3],
                                        kept[k2][4], bx1, by1, bx2, by2, ba)) f = true;
                    }
                    if (f) atomicOr(&sup0w[col >> 5], 1u << (col & 31));
                }
            }
            __syncthreads();

            if (wv == 0) {
                unsigned keptw = 0u;
                int nkv = nk0, lk = 0;
                unsigned pre0 = (lane < 4 && CH > 0) ? maskW[0][lane] : 0u;
                unsigned pre1 = (lane < 4 && CH > 1) ? maskW[1][lane] : 0u;
                for (int j = 0; j < CH && nkv < MAXDET; ++j) {
                    unsigned colw = pre0;
                    pre0 = pre1;
                    pre1 = (lane < 4 && (j + 2) < CH) ? maskW[j + 2][lane] : 0u;
                    bool hit = (keptw & colw) != 0u;
                    bool sup = __any(hit);
                    if ((sup0w[j >> 5] >> (j & 31)) & 1u) sup = true;
                    if (!sup) {
                        if (lane == (j >> 5)) keptw |= 1u << (j & 31);
                        if (lane == 0) klist[lk] = j;
                        lk++; nkv++;
                    }
                }
                if (lane == 0) { s_localk = lk; s_nk = nkv; }
            }
            __syncthreads();

            int lk = s_localk;
            for (int t2 = tid; t2 < lk; t2 += 1024) {
                int i = klist[t2];
                int oidx = nk0 + t2;
                kept[oidx][0] = cbox[i][0]; kept[oidx][1] = cbox[i][1];
                kept[oidx][2] = cbox[i][2]; kept[oidx][3] = cbox[i][3];
                kept[oidx][4] = cbox[i][4];
                unsigned long long kk = skeys[c0 + i];
                unsigned bits = (unsigned)(kk >> 32);
                unsigned flat = 0xFFFFFFFFu - (unsigned)kk;
                unsigned bi = flat / (unsigned)NCLS;
                unsigned cc = flat - bi * (unsigned)NCLS;
                const float* rp = pb + (size_t)bi * ROWF;
                float cx = rp[0], cy = rp[1], wd = rp[2], ht = rp[3];
                float hw = __fmul_rn(0.5f, wd), hh = __fmul_rn(0.5f, ht);
                float* orow = ob + (size_t)oidx * 6;
                orow[0] = __fsub_rn(cx, hw);
                orow[1] = __fsub_rn(cy, hh);
                orow[2] = __fadd_rn(cx, hw);
                orow[3] = __fadd_rn(cy, hh);
                orow[4] = __uint_as_float(bits);
                orow[5] = (float)cc;
            }
            __syncthreads();
        }
        p = gEnd;
    }
#undef GSV
}

// ---------------- launch --------------------------------------------------------------
extern "C" void kernel_launch(void* const* d_in, const int* in_sizes, int n_in,
                              void* d_out, int out_size, void* d_ws, size_t ws_size,
                              hipStream_t stream) {
    const float* pred = (const float*)d_in[0];
    float* outp = (float*)d_out;
    char* ws = (char*)d_ws;

    // zeroed region (contiguous)
    const size_t OFF_HIST  = 0;
    const size_t SZ_HIST   = (size_t)BATCH * NBIN * 4;               // 196,608
    const size_t OFF_CUR   = OFF_HIST + SZ_HIST;
    const size_t SZ_CUR    = (size_t)BATCH * NBIN * 4;               // 196,608
    const size_t OFF_H2    = OFF_CUR + SZ_CUR;
    const size_t SZ_H2     = (size_t)BATCH * NBUCK * 4;              // 65,536
    const size_t OFF_CCNT  = OFF_H2 + SZ_H2;
    const size_t SZ_CCNT   = (size_t)BATCH * 4;
    const size_t OFF_OFLW  = OFF_CCNT + SZ_CCNT;
    const size_t SZ_OFLW   = (size_t)BATCH * 4;
    const size_t OFF_META  = OFF_OFLW + SZ_OFLW;
    const size_t SZ_META   = (size_t)BATCH * 8 * 4;
    const size_t ZERO_SZ   = OFF_META + SZ_META;
    // non-zeroed
    const size_t OFF_SUF   = ZERO_SZ;
    const size_t SZ_SUF    = (size_t)BATCH * (NBIN + 1) * 4;
    const size_t OFF_SUF2  = OFF_SUF + SZ_SUF;
    const size_t SZ_SUF2   = (size_t)BATCH * (NBUCK + 1) * 4;
    const size_t OFF_KEYS  = OFF_SUF2 + SZ_SUF2;
    const size_t SZ_KEYS   = (size_t)BATCH * CAP * 8;                // 4,194,304
    const size_t OFF_K2    = OFF_KEYS + SZ_KEYS;
    const size_t SZ_K2     = (size_t)BATCH * K2CAP * 8;              // 524,288
    const size_t OFF_CAND  = OFF_K2 + SZ_K2;
    const size_t SZ_CAND   = (size_t)BATCH * CANDCAP * 8;            // 16,777,216
    const size_t WS_NEEDED = OFF_CAND + SZ_CAND;                     // ~22.4 MB

    int staged = (ws_size >= WS_NEEDED) ? 1 : 0;

    unsigned* hist             = (unsigned*)(ws + OFF_HIST);
    unsigned* cursor           = (unsigned*)(ws + OFF_CUR);
    unsigned* hist2            = (unsigned*)(ws + OFF_H2);
    unsigned* ccnt             = (unsigned*)(ws + OFF_CCNT);
    unsigned* oflow            = (unsigned*)(ws + OFF_OFLW);
    int* meta                  = (int*)(ws + OFF_META);
    unsigned* suf              = (unsigned*)(ws + OFF_SUF);
    unsigned* suf2             = (unsigned*)(ws + OFF_SUF2);
    unsigned long long* keys   = (unsigned long long*)(ws + OFF_KEYS);
    unsigned long long* keys2  = (unsigned long long*)(ws + OFF_K2);
    unsigned long long* cand   = (unsigned long long*)(ws + OFF_CAND);

    hipMemsetAsync(ws, 0, ZERO_SZ, stream);
    hipMemsetAsync(d_out, 0, (size_t)out_size * sizeof(float), stream);

    k_stage<<<dim3(BATCH * SBLK2), dim3(512), 0, stream>>>(pred, hist2, ccnt, cand, oflow, staged);
    k_prep<<<dim3(BATCH), dim3(1024), 0, stream>>>(hist2, ccnt, oflow, cand, suf2, keys2, meta, staged);
    k_hist_fb<<<dim3(BATCH * SBLK), dim3(256), 0, stream>>>(pred, hist, meta);
    k_scan_fb<<<dim3(BATCH), dim3(256), 0, stream>>>(hist, suf, meta);
    k_scatter_fb<<<dim3(BATCH * SBLK), dim3(256), 0, stream>>>(pred, suf, meta, cursor, keys);
    k_nms<<<dim3(BATCH), dim3(1024), 0, stream>>>(pred, suf, suf2, meta, ccnt, keys, keys2, cand, outp);
}

// Round 6
// 323.328 us; speedup vs baseline: 1.0136x; 1.0136x over previous
//
#include <hip/hip_runtime.h>
#include <stdint.h>

#define BATCH 16
#define NROW 25200
#define NCLS 80
#define ROWF 85
#define MAXDET 300
#define MAXNMS 30000u
#define NBIN 3072
#define BASEBITS 0x3EC00000u
#define CAP 32768u
#define BATCH_FLOATS 2142000   // 25200*85

#define PREBIN 2048            // score >= 0.75
#define NBUCK 1024             // NBIN - PREBIN
#define CANDCAP 131072u
#define TOPK 2048u             // target size of the pre-ordered head
#define K2CAP 4096u            // TOPK + max bin (1024) + slack

#define SORTCAP 1024
#define CH_SZ 128

// fallback tiling (k_hist_fb / k_scatter_fb)
#define TILE_ROWS 80
#define TILE_FLOATS 6800
#define RPB 400
#define SUBT 5
#define SBLK 63

// k_stage geometry (round-4 PROVEN): 70 blocks/batch x 360 rows; per-wave private
// 12-row chunks (12*85 = 1020 floats = 255 f4), 2 buffers/wave of 256 f4 stride
// (1 pad f4), 4 full-wave clamped DMAs per chunk, vmcnt(0) self-sync
#define SBLK2 70
#define RPB2 360
#define CH2 30                 // 12-row chunks per block
#define CH_F4 255u             // f4 per chunk
#define BLK2_F4 7650u          // RPB2*85/4
#define B_F4 535500u           // BATCH_FLOATS/4
#define TOTAL_F4 8568000u      // BATCH*B_F4
#define KMAXS 1536u            // per-block candidate cap (avg ~985 @360 rows)

// exact: fl(inter/den) > 0.5, division only at the rounding boundary
__device__ __forceinline__ bool iou_gt_half(float ax1, float ay1, float ax2, float ay2, float aa,
                                            float bx1, float by1, float bx2, float by2, float ba) {
    float ltx = fmaxf(ax1, bx1), lty = fmaxf(ay1, by1);
    float rbx = fminf(ax2, bx2), rby = fminf(ay2, by2);
    float wx = fmaxf(__fsub_rn(rbx, ltx), 0.0f);
    float wy = fmaxf(__fsub_rn(rby, lty), 0.0f);
    float inter = __fmul_rn(wx, wy);
    float den = __fadd_rn(__fsub_rn(__fadd_rn(aa, ba), inter), 1e-9f);
    float t = __fmul_rn(0.5f, den);
    if (!(inter > t)) return false;
    float tg = __fmul_rn(0.50000012f, den);
    if (inter >= tg) return true;
    return __fdiv_rn(inter, den) > 0.5f;
}

__device__ __forceinline__ unsigned bin_of_bits(unsigned bits) {
    unsigned v = (bits - BASEBITS) >> 12;
    if (v > (unsigned)(NBIN - 1)) v = NBIN - 1;
    return v;
}

// async global->LDS DMA: 16B per lane, LDS dest = wave-uniform base + lane*16
__device__ __forceinline__ void gload_lds16(const float4* g, float* lds_base_wave_uniform) {
    __builtin_amdgcn_global_load_lds((const __attribute__((address_space(1))) void*)g,
                                     (__attribute__((address_space(3))) void*)lds_base_wave_uniform,
                                     16, 0, 0);
}

// issue one 12-row chunk (255 f4 + 1 pad f4) into this wave's private buffer:
// 4 FULL-WAVE DMAs with clamped global addresses (round-5's lane-predicated third
// DMA was the prime suspect for the correctness failure — EXEC-partial global_load_lds
// is unverified HW behavior; full-wave + clamp is the m97-proven form)
__device__ __forceinline__ void issue_chunk(const float4* __restrict__ predf4,
                                            float* wbuf, unsigned chunk_f4_base, int lane) {
    #pragma unroll
    for (int j = 0; j < 4; ++j) {
        unsigned gi = chunk_f4_base + (unsigned)(j << 6) + (unsigned)lane;
        if (gi > TOTAL_F4 - 1u) gi = TOTAL_F4 - 1u;   // pad lane / tensor tail clamp
        gload_lds16(predf4 + gi, wbuf + (size_t)(j << 8));   // j*64 f4 = j*256 floats
    }
}

// ---------------- K1: barrier-free per-wave streaming filter, v4 ---------------------
// Round-4 evidence: L3-resident runs took the SAME 80us as HBM-fed -> bound by
// per-wave chains, not memory supply. v4 = round-4 proven DMA structure + three
// chain-cuts: (1) obj>=0.75 row gate (identical candidate set: s=fl(cls*obj)<=obj by
// monotone rounding, so s>=0.75 => obj>=0.75; live rows 0.60->0.25); (2) batched obj
// reads (12 independent ds_reads pipeline vs 12 serial ~120cy chains); (3) ONE s_cnt
// atomic per live row (segment-1 slots offset by popc(m0); set-identical, and all
// downstream consumers rank-sort by full key so order is irrelevant).
__global__ __launch_bounds__(512) void k_stage(const float* __restrict__ pred,
                                               unsigned* __restrict__ hist2,
                                               unsigned* __restrict__ ccnt,
                                               unsigned long long* __restrict__ cand,
                                               unsigned* __restrict__ oflow,
                                               int staged) {
    if (!staged) return;
    __shared__ __align__(16) float rows[8 * 2 * 1024];   // 8 waves x 2 bufs x 256 f4 = 64 KB
    __shared__ unsigned shist32[NBUCK / 2];              // 2 x u16 packed per word (2 KB)
    __shared__ unsigned long long skey[KMAXS];           // 12 KB
    __shared__ unsigned s_cnt, s_n, s_base;
    int bx = blockIdx.x;
    int b = bx / SBLK2, blk = bx - b * SBLK2;
    int t = threadIdx.x, lane = t & 63, wv = t >> 6;
    if (t < NBUCK / 2) shist32[t] = 0u;
    if (t == 0) s_cnt = 0u;

    const float4* predf4 = (const float4*)pred;
    unsigned tb0 = (unsigned)b * B_F4 + (unsigned)blk * BLK2_F4;
    int rowbase = blk * RPB2;
    float* wbase = rows + (wv << 11);          // wave's 2048-float (2x256 f4) region

    // prologue: this wave's first chunk -> buf0
    issue_chunk(predf4, wbase, tb0 + (unsigned)wv * CH_F4, lane);
    __syncthreads();   // publishes shist init; drains prologue DMA (vmcnt0 per wave)

    int buf = 0;
    for (int c = wv; c < CH2; c += 8) {
        int nc = c + 8;
        if (nc < CH2)
            issue_chunk(predf4, wbase + ((buf ^ 1) << 10), tb0 + (unsigned)nc * CH_F4, lane);

        const float* rb = wbase + (buf << 10);
        // batched obj reads: 12 independent ds_reads pipeline together
        float ob[12];
        #pragma unroll
        for (int r = 0; r < 12; ++r) ob[r] = rb[r * ROWF + 4];
        #pragma unroll
        for (int r = 0; r < 12; ++r) {
            float obj = ob[r];
            if (!(obj >= 0.75f)) continue;   // exact: s>=0.75 requires obj>=0.75
            unsigned grow = (unsigned)(rowbase + c * 12 + r);
            // both segments' scores + ballots first; ONE allocation for the row
            float s0 = __fmul_rn(rb[r * ROWF + 5 + lane], obj);      // exact op order
            bool h0 = (s0 >= 0.75f);
            float s1 = 0.0f; bool h1 = false;
            if (lane < 16) {
                s1 = __fmul_rn(rb[r * ROWF + 69 + lane], obj);       // cols 69..84
                h1 = (s1 >= 0.75f);
            }
            unsigned long long m0 = __ballot(h0);
            unsigned long long m1 = __ballot(h1);
            unsigned long long ma = m0 | m1;
            if (ma) {
                unsigned p0 = (unsigned)__popcll(m0);
                unsigned tot = p0 + (unsigned)__popcll(m1);
                unsigned base = 0;
                int lead = (int)__builtin_ctzll(ma);
                if (lane == lead) base = atomicAdd(&s_cnt, tot);
                base = (unsigned)__shfl((int)base, lead);
                if (base + tot > KMAXS) oflow[b] = 1u;
                unsigned long long lt = (1ULL << lane) - 1ULL;
                if (h0) {
                    unsigned bits = __float_as_uint(s0);
                    unsigned bin = bin_of_bits(bits) - PREBIN;
                    atomicAdd(&shist32[bin >> 1], 1u << ((bin & 1) << 4));
                    unsigned u = base + (unsigned)__popcll(m0 & lt);
                    unsigned flat = grow * (unsigned)NCLS + (unsigned)lane;
                    if (u < KMAXS)
                        skey[u] = ((unsigned long long)bits << 32) |
                                  (unsigned long long)(0xFFFFFFFFu - flat);
                }
                if (h1) {
                    unsigned bits = __float_as_uint(s1);
                    unsigned bin = bin_of_bits(bits) - PREBIN;
                    atomicAdd(&shist32[bin >> 1], 1u << ((bin & 1) << 4));
                    unsigned u = base + p0 + (unsigned)__popcll(m1 & lt);
                    unsigned flat = grow * (unsigned)NCLS + (unsigned)(64 + lane);
                    if (u < KMAXS)
                        skey[u] = ((unsigned long long)bits << 32) |
                                  (unsigned long long)(0xFFFFFFFFu - flat);
                }
            }
        }
        if (nc < CH2) {
            asm volatile("s_waitcnt vmcnt(0)" ::: "memory");   // own next-chunk DMA done
        }
        buf ^= 1;
    }

    __syncthreads();   // all waves done producing shist/skey/s_cnt

    // flush block-local hist (unpack 2xu16) + candidate buffer (unchanged semantics)
    unsigned* gh = hist2 + (size_t)b * NBUCK;
    if (t < NBUCK / 2) {
        unsigned w = shist32[t];
        unsigned lo = w & 0xFFFFu, hi = w >> 16;
        if (lo) atomicAdd(&gh[2 * t], lo);
        if (hi) atomicAdd(&gh[2 * t + 1], hi);
    }
    if (t == 0) {
        unsigned n = s_cnt;
        if (n > KMAXS) n = KMAXS;
        unsigned base = atomicAdd(&ccnt[b], n);
        if (base + n > CANDCAP) oflow[b] = 1u;
        s_n = n; s_base = base;
    }
    __syncthreads();
    unsigned n = s_n, base = s_base;
    if (base + n <= CANDCAP) {
        unsigned long long* cd = cand + (size_t)b * CANDCAP + base;
        for (unsigned k = t; k < n; k += 512) cd[k] = skey[k];
    }
}

// ---------------- K2: scan hist -> meta + suf2, scatter top-TOPK into keys2 ----------
__global__ __launch_bounds__(1024) void k_prep(const unsigned* __restrict__ hist2,
                                               const unsigned* __restrict__ ccnt,
                                               const unsigned* __restrict__ oflow,
                                               const unsigned long long* __restrict__ cand,
                                               unsigned* __restrict__ suf2,
                                               unsigned long long* __restrict__ keys2,
                                               int* __restrict__ meta,
                                               int staged) {
    __shared__ unsigned sS[NBUCK];
    __shared__ unsigned scur[NBUCK];
    __shared__ int s_cut, s_need, s_tot, s_T, s_valid;
    __shared__ unsigned s_bad, s_E;
    int b = blockIdx.x, t = threadIdx.x;   // 1024 threads == NBUCK
    unsigned h = hist2[(size_t)b * NBUCK + t];
    sS[t] = h;
    if (t == 0) { s_cut = -1; s_T = -1; s_bad = 0u; s_need = 0; s_tot = 0; s_E = 0u; }
    __syncthreads();
    if (h > (unsigned)SORTCAP) atomicOr(&s_bad, 1u);
    for (int off = 1; off < NBUCK; off <<= 1) {
        unsigned v = (t + off < NBUCK) ? sS[t + off] : 0u;
        __syncthreads();
        sS[t] += v;
        __syncthreads();
    }
    unsigned Sv = sS[t];
    unsigned Sn = (t + 1 < NBUCK) ? sS[t + 1] : 0u;
    if (Sv >= MAXNMS && Sn < MAXNMS) {
        s_cut = PREBIN + t; s_need = (int)(MAXNMS - Sn); s_tot = (int)Sv;
    }
    if (Sv >= TOPK && Sn < TOPK) { s_T = PREBIN + t; s_E = Sv; }
    unsigned* g2 = suf2 + (size_t)b * (NBUCK + 1);
    g2[t] = Sv;
    if (t == 0) g2[NBUCK] = 0u;
    scur[t] = Sn;                      // scatter base for bin PREBIN+t = S(v+1)
    __syncthreads();
    if (t == 0) {
        int valid = (staged && s_cut >= 0 && s_T >= 0 && s_bad == 0u &&
                     oflow[b] == 0u && ccnt[b] <= CANDCAP) ? 1 : 0;
        s_valid = valid;
        meta[b * 8 + 0] = valid ? s_cut : 0;
        meta[b * 8 + 1] = valid ? s_need : 0;
        meta[b * 8 + 2] = valid ? s_tot : 0;
        meta[b * 8 + 3] = valid;
        meta[b * 8 + 4] = valid ? s_T : 0;
        meta[b * 8 + 5] = valid ? (int)s_E : 0;
    }
    __syncthreads();
    if (s_valid) {
        int T = s_T;
        unsigned ccb = ccnt[b];
        const unsigned long long* cd = cand + (size_t)b * CANDCAP;
        unsigned long long* k2 = keys2 + (size_t)b * K2CAP;
        for (unsigned k = t; k < ccb; k += 1024) {
            unsigned long long key = cd[k];
            unsigned v = bin_of_bits((unsigned)(key >> 32));
            if ((int)v >= T) {
                unsigned pos = atomicAdd(&scur[v - PREBIN], 1u);
                if (pos < K2CAP) k2[pos] = key;
            }
        }
    }
}

// ---------------- K3a (fallback): full histogram ------------------------------------
__global__ __launch_bounds__(256) void k_hist_fb(const float* __restrict__ pred,
                                                 unsigned* __restrict__ hist,
                                                 const int* __restrict__ meta) {
    int bx = blockIdx.x;
    int b = bx / SBLK, blk = bx - b * SBLK;
    if (meta[b * 8 + 3]) return;
    __shared__ __align__(16) float rows[TILE_FLOATS];
    __shared__ unsigned shist[NBIN];
    int t = threadIdx.x, lane = t & 63, wv = t >> 6;
    for (int i = t; i < NBIN; i += 256) shist[i] = 0u;
    const float* pbase = pred + (size_t)b * BATCH_FLOATS + (size_t)blk * RPB * ROWF;
    for (int st = 0; st < SUBT; ++st) {
        __syncthreads();
        const float4* src = (const float4*)(pbase + (size_t)st * TILE_ROWS * ROWF);
        float4* dst = (float4*)rows;
        for (int i = t; i < TILE_FLOATS / 4; i += 256) dst[i] = src[i];
        __syncthreads();
        for (int r = wv; r < TILE_ROWS; r += 4) {
            float obj = rows[r * ROWF + 4];
            if (!(obj > 0.4f)) continue;
            for (int half = 0; half < 2; ++half) {
                int c = lane + (half << 6);
                if (c < NCLS) {
                    float s = __fmul_rn(rows[r * ROWF + 5 + c], obj);
                    if (s > 0.4f) atomicAdd(&shist[bin_of_bits(__float_as_uint(s))], 1u);
                }
            }
        }
    }
    __syncthreads();
    unsigned* gh = hist + (size_t)b * NBIN;
    for (int i = t; i < NBIN; i += 256) {
        unsigned v = shist[i];
        if (v) atomicAdd(&gh[i], v);
    }
}

// ---------------- K3b (fallback): suffix-scan full hist -> meta + suf ----------------
__global__ __launch_bounds__(256) void k_scan_fb(const unsigned* __restrict__ hist,
                                                 unsigned* __restrict__ suf,
                                                 int* __restrict__ meta) {
    int b = blockIdx.x, t = threadIdx.x;
    if (meta[b * 8 + 3]) return;
    __shared__ unsigned sh[NBIN];
    __shared__ unsigned sS[NBIN];
    __shared__ unsigned cs[256];
    __shared__ int s_cut, s_need, s_tot;
    const unsigned* gh = hist + (size_t)b * NBIN;
    for (int i = t; i < NBIN; i += 256) sh[i] = gh[i];
    if (t == 0) { s_cut = 0; s_need = 0x7FFFFFFF; s_tot = 0; }
    __syncthreads();
    const int CHUNK = NBIN / 256;
    int base = t * CHUNK;
    unsigned tot = 0;
    for (int i = 0; i < CHUNK; ++i) tot += sh[base + i];
    cs[t] = tot;
    __syncthreads();
    for (int off = 1; off < 256; off <<= 1) {
        unsigned v = (t + off < 256) ? cs[t + off] : 0u;
        __syncthreads();
        cs[t] += v;
        __syncthreads();
    }
    unsigned after = (t + 1 < 256) ? cs[t + 1] : 0u;
    for (int i = CHUNK - 1; i >= 0; --i) {
        after += sh[base + i];
        sS[base + i] = after;
    }
    __syncthreads();
    unsigned* gs = suf + (size_t)b * (NBIN + 1);
    for (int i = t; i < NBIN; i += 256) gs[i] = sS[i];
    if (t == 0) gs[NBIN] = 0u;
    for (int i = 0; i < CHUNK; ++i) {
        int v = base + i;
        unsigned Sv = sS[v];
        unsigned Sn = (v + 1 < NBIN) ? sS[v + 1] : 0u;
        if (Sv >= MAXNMS && Sn < MAXNMS) {
            s_cut = v; s_need = (int)(MAXNMS - Sn); s_tot = (int)Sv;
        }
    }
    __syncthreads();
    if (t == 0) {
        int cut = s_cut, needv = s_need, totv = s_tot;
        if (sS[0] < MAXNMS) { cut = 0; needv = 0x7FFFFFFF; totv = (int)sS[0]; }
        meta[b * 8 + 0] = cut;
        meta[b * 8 + 1] = needv;
        meta[b * 8 + 2] = totv;
    }
}

// ---------------- K3c (fallback): full re-read counting-scatter ----------------------
__global__ __launch_bounds__(256) void k_scatter_fb(const float* __restrict__ pred,
                                                    const unsigned* __restrict__ suf,
                                                    const int* __restrict__ meta,
                                                    unsigned* __restrict__ cursor,
                                                    unsigned long long* __restrict__ keys) {
    int bx = blockIdx.x;
    int b = bx / SBLK, blk = bx - b * SBLK;
    if (meta[b * 8 + 3]) return;
    __shared__ __align__(16) float rows[TILE_FLOATS];
    int t = threadIdx.x, lane = t & 63, wv = t >> 6;
    int cutbin = meta[b * 8 + 0];
    const float* pbase = pred + (size_t)b * BATCH_FLOATS + (size_t)blk * RPB * ROWF;
    unsigned rowbase0 = (unsigned)(blk * RPB);
    const unsigned* gs = suf + (size_t)b * (NBIN + 1);
    unsigned* cur = cursor + (size_t)b * NBIN;
    unsigned long long* kb = keys + (size_t)b * CAP;
    for (int st = 0; st < SUBT; ++st) {
        __syncthreads();
        const float4* src = (const float4*)(pbase + (size_t)st * TILE_ROWS * ROWF);
        float4* dst = (float4*)rows;
        for (int i = t; i < TILE_FLOATS / 4; i += 256) dst[i] = src[i];
        __syncthreads();
        for (int r = wv; r < TILE_ROWS; r += 4) {
            float obj = rows[r * ROWF + 4];
            if (!(obj > 0.4f)) continue;
            unsigned grow = rowbase0 + (unsigned)(st * TILE_ROWS + r);
            for (int half = 0; half < 2; ++half) {
                int c = lane + (half << 6);
                if (c < NCLS) {
                    float s = __fmul_rn(rows[r * ROWF + 5 + c], obj);
                    if (s > 0.4f) {
                        unsigned bits = __float_as_uint(s);
                        unsigned bin = bin_of_bits(bits);
                        if ((int)bin >= cutbin) {
                            unsigned pos = gs[bin + 1] + atomicAdd(&cur[bin], 1u);
                            if (pos < CAP) {
                                unsigned flat = grow * (unsigned)NCLS + (unsigned)c;
                                kb[pos] = ((unsigned long long)bits << 32) |
                                          (unsigned long long)(0xFFFFFFFFu - flat);
                            }
                        }
                    }
                }
            }
        }
    }
}

// ---------------- K4: NMS — contiguous keys2 gather, in-bin rank, 128-chunk mask -----
__global__ __launch_bounds__(1024) void k_nms(const float* __restrict__ pred,
                                              const unsigned* __restrict__ suf,
                                              const unsigned* __restrict__ suf2,
                                              const int* __restrict__ meta,
                                              const unsigned* __restrict__ ccnt,
                                              const unsigned long long* __restrict__ keys,
                                              const unsigned long long* __restrict__ keys2,
                                              const unsigned long long* __restrict__ cand,
                                              float* __restrict__ out) {
    __shared__ unsigned sgsL[NBUCK + 1];
    __shared__ unsigned long long ktmp[SORTCAP];
    __shared__ unsigned long long skeys[SORTCAP];
    __shared__ unsigned maskW[CH_SZ][5];
    __shared__ unsigned sup0w[4];
    __shared__ float cbox[CH_SZ][9];
    __shared__ float kept[MAXDET][5];
    __shared__ int klist[MAXDET];
    __shared__ int s_nk, s_localk;
    __shared__ unsigned s_gc;

    int b = blockIdx.x;
    int tid = threadIdx.x;
    int lane = tid & 63, wv = tid >> 6;

    int cutbin = meta[b * 8 + 0];
    int needv  = meta[b * 8 + 1];
    unsigned total = (unsigned)meta[b * 8 + 2];
    int valid  = meta[b * 8 + 3];
    int Tbin   = meta[b * 8 + 4];
    unsigned E = valid ? (unsigned)meta[b * 8 + 5] : 0u;
    if (!valid && total > CAP) total = CAP;
    const unsigned* gs = suf + (size_t)b * (NBIN + 1);
    const unsigned* g2 = suf2 + (size_t)b * (NBUCK + 1);
    const unsigned long long* kb = keys + (size_t)b * CAP;
    const unsigned long long* k2 = keys2 + (size_t)b * K2CAP;
    const unsigned long long* cd = cand + (size_t)b * CANDCAP;
    unsigned ccb = valid ? ccnt[b] : 0u;
    if (ccb > CANDCAP) ccb = CANDCAP;
    const float* pb = pred + (size_t)b * BATCH_FLOATS;
    float* ob = out + (size_t)b * MAXDET * 6;

    if (valid) for (int i = tid; i < NBUCK + 1; i += 1024) sgsL[i] = g2[i];
    if (tid == 0) s_nk = 0;
    __syncthreads();

#define GSV(v) (valid ? sgsL[(v) - PREBIN] : gs[(v)])

    unsigned limit;
    if (needv == 0x7FFFFFFF) limit = total;
    else limit = GSV(cutbin + 1) + (unsigned)needv;
    if (limit > total) limit = total;

    unsigned p = 0;
    while (p < limit) {
        if (s_nk >= MAXDET) break;

        // vs = smallest v with GSV(v) <= p + SORTCAP  -> maximal whole-bin extent
        int lo = cutbin, hi = NBIN - 1, vs = NBIN - 1;
        while (lo <= hi) { int mid = (lo + hi) >> 1;
            if (GSV(mid) <= p + (unsigned)SORTCAP) { vs = mid; hi = mid - 1; } else lo = mid + 1; }
        unsigned gEnd = GSV(vs);
        bool phaseA = (!valid) || (p < E);
        if (valid && phaseA && gEnd > E) gEnd = E;
        if (gEnd > total) gEnd = total;
        if (gEnd <= p) { gEnd = p + (unsigned)SORTCAP; if (gEnd > total) gEnd = total; }  // defensive
        unsigned G = gEnd - p;

        if (phaseA) {
            // dense bin-partitioned source indexed by absolute rank
            const unsigned long long* src = valid ? k2 : kb;
            unsigned myLo = 0, myHi = 0;
            unsigned long long raw = 0ULL;
            if (tid < (int)G) {
                unsigned idx = p + (unsigned)tid;
                int l2 = cutbin, h2 = NBIN - 1, v = cutbin;
                while (l2 <= h2) { int mid = (l2 + h2) >> 1;
                    if (GSV(mid) > idx) { v = mid; l2 = mid + 1; } else h2 = mid - 1; }
                unsigned bstart = GSV(v + 1);
                unsigned bend = GSV(v);
                raw = src[idx];
                myLo = (bstart > p) ? (bstart - p) : 0u;
                myHi = bend - p; if (myHi > G) myHi = G;
                ktmp[tid] = raw;
            }
            __syncthreads();
            if (tid < (int)G) {
                unsigned rank = 0;
                for (unsigned u = myLo; u < myHi; ++u) rank += (ktmp[u] > raw) ? 1u : 0u;
                skeys[myLo + rank] = raw;
            }
            __syncthreads();
        } else {
            // phase B (rare): filter-scan dense array for bins [vs, w1]
            int l0 = cutbin, h0 = NBIN - 1, w1 = cutbin;
            while (l0 <= h0) { int mid = (l0 + h0) >> 1;
                if (GSV(mid) > p) { w1 = mid; l0 = mid + 1; } else h0 = mid - 1; }
            if (tid == 0) s_gc = 0u;
            __syncthreads();
            for (unsigned k = tid; k < ccb; k += 1024) {
                unsigned long long key = cd[k];
                unsigned v = bin_of_bits((unsigned)(key >> 32));
                if ((int)v >= vs && (int)v <= w1) {
                    unsigned u = atomicAdd(&s_gc, 1u);
                    if (u < (unsigned)SORTCAP) ktmp[u] = key;
                }
            }
            __syncthreads();
            unsigned Gc = s_gc; if (Gc > (unsigned)SORTCAP) Gc = (unsigned)SORTCAP;
            if (tid < (int)Gc) {
                unsigned long long key = ktmp[tid];
                unsigned v = bin_of_bits((unsigned)(key >> 32));
                unsigned bstart = GSV(v + 1);
                unsigned rank = 0;
                for (unsigned u = 0; u < Gc; ++u) {
                    unsigned long long kk = ktmp[u];
                    unsigned vu = bin_of_bits((unsigned)(kk >> 32));
                    rank += (vu == v && kk > key) ? 1u : 0u;
                }
                skeys[(bstart - p) + rank] = key;
            }
            __syncthreads();
        }

        unsigned consumable = limit - p; if (consumable > G) consumable = G;

        for (unsigned c0 = 0; c0 < consumable; c0 += CH_SZ) {
            int nk0 = s_nk;
            if (nk0 >= MAXDET) break;
            int CH = (int)((consumable - c0 < (unsigned)CH_SZ) ? (consumable - c0) : (unsigned)CH_SZ);

            if (tid < CH_SZ * 5) maskW[tid / 5][tid % 5] = 0u;
            if (tid >= CH_SZ * 5 && tid < CH_SZ * 5 + 4) sup0w[tid - CH_SZ * 5] = 0u;
            if (tid < CH) {
                unsigned long long kk = skeys[c0 + tid];
                unsigned flat = 0xFFFFFFFFu - (unsigned)kk;
                unsigned bi = flat / (unsigned)NCLS;
                unsigned cc = flat - bi * (unsigned)NCLS;
                const float* rp = pb + (size_t)bi * ROWF;
                float cx = rp[0], cy = rp[1], wd = rp[2], ht = rp[3];
                float hw = __fmul_rn(0.5f, wd), hh = __fmul_rn(0.5f, ht);
                float off = __fmul_rn((float)cc, 4096.0f);
                float x1 = __fsub_rn(cx, hw), y1 = __fsub_rn(cy, hh);
                float x2 = __fadd_rn(cx, hw), y2 = __fadd_rn(cy, hh);
                float ox1 = __fadd_rn(x1, off), oy1 = __fadd_rn(y1, off);
                float ox2 = __fadd_rn(x2, off), oy2 = __fadd_rn(y2, off);
                cbox[tid][0] = ox1; cbox[tid][1] = oy1;
                cbox[tid][2] = ox2; cbox[tid][3] = oy2;
                cbox[tid][4] = __fmul_rn(__fsub_rn(ox2, ox1), __fsub_rn(oy2, oy1));
            }
            __syncthreads();

            {
                int col = tid & (CH_SZ - 1);
                int part = tid >> 7;
                if (col < CH) {
                    float bx1 = cbox[col][0], by1 = cbox[col][1];
                    float bx2 = cbox[col][2], by2 = cbox[col][3], ba = cbox[col][4];
                    unsigned part16 = 0u;
                    int rbase = part << 4;
                    for (int k = 0; k < 16; ++k) {
                        int i2 = rbase + k;
                        if (i2 >= col || i2 >= CH) break;
                        if (iou_gt_half(cbox[i2][0], cbox[i2][1], cbox[i2][2], cbox[i2][3],
                                        cbox[i2][4], bx1, by1, bx2, by2, ba))
                            part16 |= (1u << k);
                    }
                    if (part16)
                        atomicOr(&maskW[col][part >> 1], part16 << ((part & 1) << 4));
                    bool f = false;
                    for (int k2 = part; k2 < nk0; k2 += 8) {
                        if (iou_gt_half(kept[k2][0], kept[k2][1], kept[k2][2], kept[k2][3],
                                        kept[k2][4], bx1, by1, bx2, by2, ba)) f = true;
                    }
                    if (f) atomicOr(&sup0w[col >> 5], 1u << (col & 31));
                }
            }
            __syncthreads();

            if (wv == 0) {
                unsigned keptw = 0u;
                int nkv = nk0, lk = 0;
                unsigned pre0 = (lane < 4 && CH > 0) ? maskW[0][lane] : 0u;
                unsigned pre1 = (lane < 4 && CH > 1) ? maskW[1][lane] : 0u;
                for (int j = 0; j < CH && nkv < MAXDET; ++j) {
                    unsigned colw = pre0;
                    pre0 = pre1;
                    pre1 = (lane < 4 && (j + 2) < CH) ? maskW[j + 2][lane] : 0u;
                    bool hit = (keptw & colw) != 0u;
                    bool sup = __any(hit);
                    if ((sup0w[j >> 5] >> (j & 31)) & 1u) sup = true;
                    if (!sup) {
                        if (lane == (j >> 5)) keptw |= 1u << (j & 31);
                        if (lane == 0) klist[lk] = j;
                        lk++; nkv++;
                    }
                }
                if (lane == 0) { s_localk = lk; s_nk = nkv; }
            }
            __syncthreads();

            int lk = s_localk;
            for (int t2 = tid; t2 < lk; t2 += 1024) {
                int i = klist[t2];
                int oidx = nk0 + t2;
                kept[oidx][0] = cbox[i][0]; kept[oidx][1] = cbox[i][1];
                kept[oidx][2] = cbox[i][2]; kept[oidx][3] = cbox[i][3];
                kept[oidx][4] = cbox[i][4];
                unsigned long long kk = skeys[c0 + i];
                unsigned bits = (unsigned)(kk >> 32);
                unsigned flat = 0xFFFFFFFFu - (unsigned)kk;
                unsigned bi = flat / (unsigned)NCLS;
                unsigned cc = flat - bi * (unsigned)NCLS;
                const float* rp = pb + (size_t)bi * ROWF;
                float cx = rp[0], cy = rp[1], wd = rp[2], ht = rp[3];
                float hw = __fmul_rn(0.5f, wd), hh = __fmul_rn(0.5f, ht);
                float* orow = ob + (size_t)oidx * 6;
                orow[0] = __fsub_rn(cx, hw);
                orow[1] = __fsub_rn(cy, hh);
                orow[2] = __fadd_rn(cx, hw);
                orow[3] = __fadd_rn(cy, hh);
                orow[4] = __uint_as_float(bits);
                orow[5] = (float)cc;
            }
            __syncthreads();
        }
        p = gEnd;
    }
#undef GSV
}

// ---------------- launch --------------------------------------------------------------
extern "C" void kernel_launch(void* const* d_in, const int* in_sizes, int n_in,
                              void* d_out, int out_size, void* d_ws, size_t ws_size,
                              hipStream_t stream) {
    const float* pred = (const float*)d_in[0];
    float* outp = (float*)d_out;
    char* ws = (char*)d_ws;

    // zeroed region (contiguous)
    const size_t OFF_HIST  = 0;
    const size_t SZ_HIST   = (size_t)BATCH * NBIN * 4;               // 196,608
    const size_t OFF_CUR   = OFF_HIST + SZ_HIST;
    const size_t SZ_CUR    = (size_t)BATCH * NBIN * 4;               // 196,608
    const size_t OFF_H2    = OFF_CUR + SZ_CUR;
    const size_t SZ_H2     = (size_t)BATCH * NBUCK * 4;              // 65,536
    const size_t OFF_CCNT  = OFF_H2 + SZ_H2;
    const size_t SZ_CCNT   = (size_t)BATCH * 4;
    const size_t OFF_OFLW  = OFF_CCNT + SZ_CCNT;
    const size_t SZ_OFLW   = (size_t)BATCH * 4;
    const size_t OFF_META  = OFF_OFLW + SZ_OFLW;
    const size_t SZ_META   = (size_t)BATCH * 8 * 4;
    const size_t ZERO_SZ   = OFF_META + SZ_META;
    // non-zeroed
    const size_t OFF_SUF   = ZERO_SZ;
    const size_t SZ_SUF    = (size_t)BATCH * (NBIN + 1) * 4;
    const size_t OFF_SUF2  = OFF_SUF + SZ_SUF;
    const size_t SZ_SUF2   = (size_t)BATCH * (NBUCK + 1) * 4;
    const size_t OFF_KEYS  = OFF_SUF2 + SZ_SUF2;
    const size_t SZ_KEYS   = (size_t)BATCH * CAP * 8;                // 4,194,304
    const size_t OFF_K2    = OFF_KEYS + SZ_KEYS;
    const size_t SZ_K2     = (size_t)BATCH * K2CAP * 8;              // 524,288
    const size_t OFF_CAND  = OFF_K2 + SZ_K2;
    const size_t SZ_CAND   = (size_t)BATCH * CANDCAP * 8;            // 16,777,216
    const size_t WS_NEEDED = OFF_CAND + SZ_CAND;                     // ~22.4 MB

    int staged = (ws_size >= WS_NEEDED) ? 1 : 0;

    unsigned* hist             = (unsigned*)(ws + OFF_HIST);
    unsigned* cursor           = (unsigned*)(ws + OFF_CUR);
    unsigned* hist2            = (unsigned*)(ws + OFF_H2);
    unsigned* ccnt             = (unsigned*)(ws + OFF_CCNT);
    unsigned* oflow            = (unsigned*)(ws + OFF_OFLW);
    int* meta                  = (int*)(ws + OFF_META);
    unsigned* suf              = (unsigned*)(ws + OFF_SUF);
    unsigned* suf2             = (unsigned*)(ws + OFF_SUF2);
    unsigned long long* keys   = (unsigned long long*)(ws + OFF_KEYS);
    unsigned long long* keys2  = (unsigned long long*)(ws + OFF_K2);
    unsigned long long* cand   = (unsigned long long*)(ws + OFF_CAND);

    hipMemsetAsync(ws, 0, ZERO_SZ, stream);
    hipMemsetAsync(d_out, 0, (size_t)out_size * sizeof(float), stream);

    k_stage<<<dim3(BATCH * SBLK2), dim3(512), 0, stream>>>(pred, hist2, ccnt, cand, oflow, staged);
    k_prep<<<dim3(BATCH), dim3(1024), 0, stream>>>(hist2, ccnt, oflow, cand, suf2, keys2, meta, staged);
    k_hist_fb<<<dim3(BATCH * SBLK), dim3(256), 0, stream>>>(pred, hist, meta);
    k_scan_fb<<<dim3(BATCH), dim3(256), 0, stream>>>(hist, suf, meta);
    k_scatter_fb<<<dim3(BATCH * SBLK), dim3(256), 0, stream>>>(pred, suf, meta, cursor, keys);
    k_nms<<<dim3(BATCH), dim3(1024), 0, stream>>>(pred, suf, suf2, meta, ccnt, keys, keys2, cand, outp);
}

// Round 8
// 315.440 us; speedup vs baseline: 1.0390x; 1.0250x over previous
//
#include <hip/hip_runtime.h>
#include <stdint.h>

#define BATCH 16
#define NROW 25200
#define NCLS 80
#define ROWF 85
#define MAXDET 300
#define MAXNMS 30000u
#define NBIN 3072
#define BASEBITS 0x3EC00000u
#define CAP 32768u
#define BATCH_FLOATS 2142000   // 25200*85

#define PREBIN 2048            // score >= 0.75
#define NBUCK 1024             // NBIN - PREBIN
#define CANDCAP 131072u
#define TOPK 2048u             // target size of the pre-ordered head
#define K2CAP 4096u            // TOPK + max bin (1024) + slack

#define SORTCAP 1024
#define CH_SZ 128

// fallback tiling (k_hist_fb / k_scatter_fb)
#define TILE_ROWS 80
#define TILE_FLOATS 6800
#define RPB 400
#define SUBT 5
#define SBLK 63

// k_stage geometry (round-4 PROVEN): 70 blocks/batch x 360 rows; per-wave private
// 12-row chunks (12*85 = 1020 floats = 255 f4), 2 buffers/wave of 256 f4 stride
// (1 pad f4), 4 full-wave clamped DMAs per chunk, vmcnt(0) self-sync
#define SBLK2 70
#define RPB2 360
#define CH2 30                 // 12-row chunks per block
#define CH_F4 255u             // f4 per chunk
#define BLK2_F4 7650u          // RPB2*85/4
#define B_F4 535500u           // BATCH_FLOATS/4
#define TOTAL_F4 8568000u      // BATCH*B_F4
#define KMAXS 1536u            // per-block candidate cap (avg ~985 @360 rows)

// exact: fl(inter/den) > 0.5, division only at the rounding boundary
__device__ __forceinline__ bool iou_gt_half(float ax1, float ay1, float ax2, float ay2, float aa,
                                            float bx1, float by1, float bx2, float by2, float ba) {
    float ltx = fmaxf(ax1, bx1), lty = fmaxf(ay1, by1);
    float rbx = fminf(ax2, bx2), rby = fminf(ay2, by2);
    float wx = fmaxf(__fsub_rn(rbx, ltx), 0.0f);
    float wy = fmaxf(__fsub_rn(rby, lty), 0.0f);
    float inter = __fmul_rn(wx, wy);
    float den = __fadd_rn(__fsub_rn(__fadd_rn(aa, ba), inter), 1e-9f);
    float t = __fmul_rn(0.5f, den);
    if (!(inter > t)) return false;
    float tg = __fmul_rn(0.50000012f, den);
    if (inter >= tg) return true;
    return __fdiv_rn(inter, den) > 0.5f;
}

__device__ __forceinline__ unsigned bin_of_bits(unsigned bits) {
    unsigned v = (bits - BASEBITS) >> 12;
    if (v > (unsigned)(NBIN - 1)) v = NBIN - 1;
    return v;
}

// read a u64 register pair from a (uniform) source lane — via __shfl, which is
// already proven on this harness (k_stage ballot-allocation path)
__device__ __forceinline__ unsigned long long readlane_u64(unsigned long long v, int l) {
    int lo = __shfl((int)(unsigned)(v & 0xFFFFFFFFu), l, 64);
    int hi = __shfl((int)(unsigned)(v >> 32), l, 64);
    return (unsigned long long)(unsigned)lo | ((unsigned long long)(unsigned)hi << 32);
}

// async global->LDS DMA: 16B per lane, LDS dest = wave-uniform base + lane*16
__device__ __forceinline__ void gload_lds16(const float4* g, float* lds_base_wave_uniform) {
    __builtin_amdgcn_global_load_lds((const __attribute__((address_space(1))) void*)g,
                                     (__attribute__((address_space(3))) void*)lds_base_wave_uniform,
                                     16, 0, 0);
}

// issue one 12-row chunk (255 f4 + 1 pad f4) into this wave's private buffer:
// 4 FULL-WAVE DMAs with clamped global addresses (m97-proven form)
__device__ __forceinline__ void issue_chunk(const float4* __restrict__ predf4,
                                            float* wbuf, unsigned chunk_f4_base, int lane) {
    #pragma unroll
    for (int j = 0; j < 4; ++j) {
        unsigned gi = chunk_f4_base + (unsigned)(j << 6) + (unsigned)lane;
        if (gi > TOTAL_F4 - 1u) gi = TOTAL_F4 - 1u;   // pad lane / tensor tail clamp
        gload_lds16(predf4 + gi, wbuf + (size_t)(j << 8));   // j*64 f4 = j*256 floats
    }
}

// ---------------- K1: barrier-free per-wave streaming filter (round-6, passing) ------
__global__ __launch_bounds__(512) void k_stage(const float* __restrict__ pred,
                                               unsigned* __restrict__ hist2,
                                               unsigned* __restrict__ ccnt,
                                               unsigned long long* __restrict__ cand,
                                               unsigned* __restrict__ oflow,
                                               int staged) {
    if (!staged) return;
    __shared__ __align__(16) float rows[8 * 2 * 1024];   // 8 waves x 2 bufs x 256 f4 = 64 KB
    __shared__ unsigned shist32[NBUCK / 2];              // 2 x u16 packed per word (2 KB)
    __shared__ unsigned long long skey[KMAXS];           // 12 KB
    __shared__ unsigned s_cnt, s_n, s_base;
    int bx = blockIdx.x;
    int b = bx / SBLK2, blk = bx - b * SBLK2;
    int t = threadIdx.x, lane = t & 63, wv = t >> 6;
    if (t < NBUCK / 2) shist32[t] = 0u;
    if (t == 0) s_cnt = 0u;

    const float4* predf4 = (const float4*)pred;
    unsigned tb0 = (unsigned)b * B_F4 + (unsigned)blk * BLK2_F4;
    int rowbase = blk * RPB2;
    float* wbase = rows + (wv << 11);          // wave's 2048-float (2x256 f4) region

    // prologue: this wave's first chunk -> buf0
    issue_chunk(predf4, wbase, tb0 + (unsigned)wv * CH_F4, lane);
    __syncthreads();   // publishes shist init; drains prologue DMA (vmcnt0 per wave)

    int buf = 0;
    for (int c = wv; c < CH2; c += 8) {
        int nc = c + 8;
        if (nc < CH2)
            issue_chunk(predf4, wbase + ((buf ^ 1) << 10), tb0 + (unsigned)nc * CH_F4, lane);

        const float* rb = wbase + (buf << 10);
        // batched obj reads: 12 independent ds_reads pipeline together
        float ob[12];
        #pragma unroll
        for (int r = 0; r < 12; ++r) ob[r] = rb[r * ROWF + 4];
        #pragma unroll
        for (int r = 0; r < 12; ++r) {
            float obj = ob[r];
            if (!(obj >= 0.75f)) continue;   // exact: s>=0.75 requires obj>=0.75
            unsigned grow = (unsigned)(rowbase + c * 12 + r);
            // both segments' scores + ballots first; ONE allocation for the row
            float s0 = __fmul_rn(rb[r * ROWF + 5 + lane], obj);      // exact op order
            bool h0 = (s0 >= 0.75f);
            float s1 = 0.0f; bool h1 = false;
            if (lane < 16) {
                s1 = __fmul_rn(rb[r * ROWF + 69 + lane], obj);       // cols 69..84
                h1 = (s1 >= 0.75f);
            }
            unsigned long long m0 = __ballot(h0);
            unsigned long long m1 = __ballot(h1);
            unsigned long long ma = m0 | m1;
            if (ma) {
                unsigned p0 = (unsigned)__popcll(m0);
                unsigned tot = p0 + (unsigned)__popcll(m1);
                unsigned base = 0;
                int lead = (int)__builtin_ctzll(ma);
                if (lane == lead) base = atomicAdd(&s_cnt, tot);
                base = (unsigned)__shfl((int)base, lead);
                if (base + tot > KMAXS) oflow[b] = 1u;
                unsigned long long lt = (1ULL << lane) - 1ULL;
                if (h0) {
                    unsigned bits = __float_as_uint(s0);
                    unsigned bin = bin_of_bits(bits) - PREBIN;
                    atomicAdd(&shist32[bin >> 1], 1u << ((bin & 1) << 4));
                    unsigned u = base + (unsigned)__popcll(m0 & lt);
                    unsigned flat = grow * (unsigned)NCLS + (unsigned)lane;
                    if (u < KMAXS)
                        skey[u] = ((unsigned long long)bits << 32) |
                                  (unsigned long long)(0xFFFFFFFFu - flat);
                }
                if (h1) {
                    unsigned bits = __float_as_uint(s1);
                    unsigned bin = bin_of_bits(bits) - PREBIN;
                    atomicAdd(&shist32[bin >> 1], 1u << ((bin & 1) << 4));
                    unsigned u = base + p0 + (unsigned)__popcll(m1 & lt);
                    unsigned flat = grow * (unsigned)NCLS + (unsigned)(64 + lane);
                    if (u < KMAXS)
                        skey[u] = ((unsigned long long)bits << 32) |
                                  (unsigned long long)(0xFFFFFFFFu - flat);
                }
            }
        }
        if (nc < CH2) {
            asm volatile("s_waitcnt vmcnt(0)" ::: "memory");   // own next-chunk DMA done
        }
        buf ^= 1;
    }

    __syncthreads();   // all waves done producing shist/skey/s_cnt

    // flush block-local hist (unpack 2xu16) + candidate buffer (unchanged semantics)
    unsigned* gh = hist2 + (size_t)b * NBUCK;
    if (t < NBUCK / 2) {
        unsigned w = shist32[t];
        unsigned lo = w & 0xFFFFu, hi = w >> 16;
        if (lo) atomicAdd(&gh[2 * t], lo);
        if (hi) atomicAdd(&gh[2 * t + 1], hi);
    }
    if (t == 0) {
        unsigned n = s_cnt;
        if (n > KMAXS) n = KMAXS;
        unsigned base = atomicAdd(&ccnt[b], n);
        if (base + n > CANDCAP) oflow[b] = 1u;
        s_n = n; s_base = base;
    }
    __syncthreads();
    unsigned n = s_n, base = s_base;
    if (base + n <= CANDCAP) {
        unsigned long long* cd = cand + (size_t)b * CANDCAP + base;
        for (unsigned k = t; k < n; k += 512) cd[k] = skey[k];
    }
}

// ---------------- K2: scan hist -> meta + suf2, scatter top-TOPK into keys2 ----------
__global__ __launch_bounds__(1024) void k_prep(const unsigned* __restrict__ hist2,
                                               const unsigned* __restrict__ ccnt,
                                               const unsigned* __restrict__ oflow,
                                               const unsigned long long* __restrict__ cand,
                                               unsigned* __restrict__ suf2,
                                               unsigned long long* __restrict__ keys2,
                                               int* __restrict__ meta,
                                               int staged) {
    __shared__ unsigned sS[NBUCK];
    __shared__ unsigned scur[NBUCK];
    __shared__ int s_cut, s_need, s_tot, s_T, s_valid;
    __shared__ unsigned s_bad, s_E;
    int b = blockIdx.x, t = threadIdx.x;   // 1024 threads == NBUCK
    unsigned h = hist2[(size_t)b * NBUCK + t];
    sS[t] = h;
    if (t == 0) { s_cut = -1; s_T = -1; s_bad = 0u; s_need = 0; s_tot = 0; s_E = 0u; }
    __syncthreads();
    if (h > (unsigned)SORTCAP) atomicOr(&s_bad, 1u);
    for (int off = 1; off < NBUCK; off <<= 1) {
        unsigned v = (t + off < NBUCK) ? sS[t + off] : 0u;
        __syncthreads();
        sS[t] += v;
        __syncthreads();
    }
    unsigned Sv = sS[t];
    unsigned Sn = (t + 1 < NBUCK) ? sS[t + 1] : 0u;
    if (Sv >= MAXNMS && Sn < MAXNMS) {
        s_cut = PREBIN + t; s_need = (int)(MAXNMS - Sn); s_tot = (int)Sv;
    }
    if (Sv >= TOPK && Sn < TOPK) { s_T = PREBIN + t; s_E = Sv; }
    unsigned* g2 = suf2 + (size_t)b * (NBUCK + 1);
    g2[t] = Sv;
    if (t == 0) g2[NBUCK] = 0u;
    scur[t] = Sn;                      // scatter base for bin PREBIN+t = S(v+1)
    __syncthreads();
    if (t == 0) {
        int valid = (staged && s_cut >= 0 && s_T >= 0 && s_bad == 0u &&
                     oflow[b] == 0u && ccnt[b] <= CANDCAP) ? 1 : 0;
        s_valid = valid;
        meta[b * 8 + 0] = valid ? s_cut : 0;
        meta[b * 8 + 1] = valid ? s_need : 0;
        meta[b * 8 + 2] = valid ? s_tot : 0;
        meta[b * 8 + 3] = valid;
        meta[b * 8 + 4] = valid ? s_T : 0;
        meta[b * 8 + 5] = valid ? (int)s_E : 0;
    }
    __syncthreads();
    if (s_valid) {
        int T = s_T;
        unsigned ccb = ccnt[b];
        const unsigned long long* cd = cand + (size_t)b * CANDCAP;
        unsigned long long* k2 = keys2 + (size_t)b * K2CAP;
        for (unsigned k = t; k < ccb; k += 1024) {
            unsigned long long key = cd[k];
            unsigned v = bin_of_bits((unsigned)(key >> 32));
            if ((int)v >= T) {
                unsigned pos = atomicAdd(&scur[v - PREBIN], 1u);
                if (pos < K2CAP) k2[pos] = key;
            }
        }
    }
}

// ---------------- K3a (fallback): full histogram ------------------------------------
__global__ __launch_bounds__(256) void k_hist_fb(const float* __restrict__ pred,
                                                 unsigned* __restrict__ hist,
                                                 const int* __restrict__ meta) {
    int bx = blockIdx.x;
    int b = bx / SBLK, blk = bx - b * SBLK;
    if (meta[b * 8 + 3]) return;
    __shared__ __align__(16) float rows[TILE_FLOATS];
    __shared__ unsigned shist[NBIN];
    int t = threadIdx.x, lane = t & 63, wv = t >> 6;
    for (int i = t; i < NBIN; i += 256) shist[i] = 0u;
    const float* pbase = pred + (size_t)b * BATCH_FLOATS + (size_t)blk * RPB * ROWF;
    for (int st = 0; st < SUBT; ++st) {
        __syncthreads();
        const float4* src = (const float4*)(pbase + (size_t)st * TILE_ROWS * ROWF);
        float4* dst = (float4*)rows;
        for (int i = t; i < TILE_FLOATS / 4; i += 256) dst[i] = src[i];
        __syncthreads();
        for (int r = wv; r < TILE_ROWS; r += 4) {
            float obj = rows[r * ROWF + 4];
            if (!(obj > 0.4f)) continue;
            for (int half = 0; half < 2; ++half) {
                int c = lane + (half << 6);
                if (c < NCLS) {
                    float s = __fmul_rn(rows[r * ROWF + 5 + c], obj);
                    if (s > 0.4f) atomicAdd(&shist[bin_of_bits(__float_as_uint(s))], 1u);
                }
            }
        }
    }
    __syncthreads();
    unsigned* gh = hist + (size_t)b * NBIN;
    for (int i = t; i < NBIN; i += 256) {
        unsigned v = shist[i];
        if (v) atomicAdd(&gh[i], v);
    }
}

// ---------------- K3b (fallback): suffix-scan full hist -> meta + suf ----------------
__global__ __launch_bounds__(256) void k_scan_fb(const unsigned* __restrict__ hist,
                                                 unsigned* __restrict__ suf,
                                                 int* __restrict__ meta) {
    int b = blockIdx.x, t = threadIdx.x;
    if (meta[b * 8 + 3]) return;
    __shared__ unsigned sh[NBIN];
    __shared__ unsigned sS[NBIN];
    __shared__ unsigned cs[256];
    __shared__ int s_cut, s_need, s_tot;
    const unsigned* gh = hist + (size_t)b * NBIN;
    for (int i = t; i < NBIN; i += 256) sh[i] = gh[i];
    if (t == 0) { s_cut = 0; s_need = 0x7FFFFFFF; s_tot = 0; }
    __syncthreads();
    const int CHUNK = NBIN / 256;
    int base = t * CHUNK;
    unsigned tot = 0;
    for (int i = 0; i < CHUNK; ++i) tot += sh[base + i];
    cs[t] = tot;
    __syncthreads();
    for (int off = 1; off < 256; off <<= 1) {
        unsigned v = (t + off < 256) ? cs[t + off] : 0u;
        __syncthreads();
        cs[t] += v;
        __syncthreads();
    }
    unsigned after = (t + 1 < 256) ? cs[t + 1] : 0u;
    for (int i = CHUNK - 1; i >= 0; --i) {
        after += sh[base + i];
        sS[base + i] = after;
    }
    __syncthreads();
    unsigned* gs = suf + (size_t)b * (NBIN + 1);
    for (int i = t; i < NBIN; i += 256) gs[i] = sS[i];
    if (t == 0) gs[NBIN] = 0u;
    for (int i = 0; i < CHUNK; ++i) {
        int v = base + i;
        unsigned Sv = sS[v];
        unsigned Sn = (v + 1 < NBIN) ? sS[v + 1] : 0u;
        if (Sv >= MAXNMS && Sn < MAXNMS) {
            s_cut = v; s_need = (int)(MAXNMS - Sn); s_tot = (int)Sv;
        }
    }
    __syncthreads();
    if (t == 0) {
        int cut = s_cut, needv = s_need, totv = s_tot;
        if (sS[0] < MAXNMS) { cut = 0; needv = 0x7FFFFFFF; totv = (int)sS[0]; }
        meta[b * 8 + 0] = cut;
        meta[b * 8 + 1] = needv;
        meta[b * 8 + 2] = totv;
    }
}

// ---------------- K3c (fallback): full re-read counting-scatter ----------------------
__global__ __launch_bounds__(256) void k_scatter_fb(const float* __restrict__ pred,
                                                    const unsigned* __restrict__ suf,
                                                    const int* __restrict__ meta,
                                                    unsigned* __restrict__ cursor,
                                                    unsigned long long* __restrict__ keys) {
    int bx = blockIdx.x;
    int b = bx / SBLK, blk = bx - b * SBLK;
    if (meta[b * 8 + 3]) return;
    __shared__ __align__(16) float rows[TILE_FLOATS];
    int t = threadIdx.x, lane = t & 63, wv = t >> 6;
    int cutbin = meta[b * 8 + 0];
    const float* pbase = pred + (size_t)b * BATCH_FLOATS + (size_t)blk * RPB * ROWF;
    unsigned rowbase0 = (unsigned)(blk * RPB);
    const unsigned* gs = suf + (size_t)b * (NBIN + 1);
    unsigned* cur = cursor + (size_t)b * NBIN;
    unsigned long long* kb = keys + (size_t)b * CAP;
    for (int st = 0; st < SUBT; ++st) {
        __syncthreads();
        const float4* src = (const float4*)(pbase + (size_t)st * TILE_ROWS * ROWF);
        float4* dst = (float4*)rows;
        for (int i = t; i < TILE_FLOATS / 4; i += 256) dst[i] = src[i];
        __syncthreads();
        for (int r = wv; r < TILE_ROWS; r += 4) {
            float obj = rows[r * ROWF + 4];
            if (!(obj > 0.4f)) continue;
            unsigned grow = rowbase0 + (unsigned)(st * TILE_ROWS + r);
            for (int half = 0; half < 2; ++half) {
                int c = lane + (half << 6);
                if (c < NCLS) {
                    float s = __fmul_rn(rows[r * ROWF + 5 + c], obj);
                    if (s > 0.4f) {
                        unsigned bits = __float_as_uint(s);
                        unsigned bin = bin_of_bits(bits);
                        if ((int)bin >= cutbin) {
                            unsigned pos = gs[bin + 1] + atomicAdd(&cur[bin], 1u);
                            if (pos < CAP) {
                                unsigned flat = grow * (unsigned)NCLS + (unsigned)c;
                                kb[pos] = ((unsigned long long)bits << 32) |
                                          (unsigned long long)(0xFFFFFFFFu - flat);
                            }
                        }
                    }
                }
            }
        }
    }
}

// ---------------- K4: NMS — transposed row-masks + register-resident greedy scan -----
// Round-6 counters: 78.4us, VALUBusy 1.3%, Occ 2.6% -> latency-chain-bound serial
// scan (per-iter LDS reads + __any). Rewrite: store the suppression mask TRANSPOSED
// (rowMW[i] = later cols i suppresses; IoU symmetric so same pair evals), preload all
// row masks into wave-0 lane registers, run the greedy with a 128-bit scalar set S and
// __shfl with uniform index (proven on this harness) -> no LDS, no cross-lane reduce
// in the chain. Kept set is bit-identical to the old forward scan.
__global__ __launch_bounds__(1024) void k_nms(const float* __restrict__ pred,
                                              const unsigned* __restrict__ suf,
                                              const unsigned* __restrict__ suf2,
                                              const int* __restrict__ meta,
                                              const unsigned* __restrict__ ccnt,
                                              const unsigned long long* __restrict__ keys,
                                              const unsigned long long* __restrict__ keys2,
                                              const unsigned long long* __restrict__ cand,
                                              float* __restrict__ out) {
    __shared__ unsigned sgsL[NBUCK + 1];
    __shared__ unsigned long long ktmp[SORTCAP];
    __shared__ unsigned long long skeys[SORTCAP];
    __shared__ __align__(16) unsigned rowMW[CH_SZ][4];   // row i -> bits of later cols it suppresses
    __shared__ unsigned sup0w[4];
    __shared__ float cbox[CH_SZ][9];
    __shared__ float kept[MAXDET][5];
    __shared__ int klist[MAXDET];
    __shared__ int s_nk, s_localk;
    __shared__ unsigned s_gc;

    int b = blockIdx.x;
    int tid = threadIdx.x;
    int lane = tid & 63, wv = tid >> 6;

    int cutbin = meta[b * 8 + 0];
    int needv  = meta[b * 8 + 1];
    unsigned total = (unsigned)meta[b * 8 + 2];
    int valid  = meta[b * 8 + 3];
    unsigned E = valid ? (unsigned)meta[b * 8 + 5] : 0u;
    if (!valid && total > CAP) total = CAP;
    const unsigned* gs = suf + (size_t)b * (NBIN + 1);
    const unsigned* g2 = suf2 + (size_t)b * (NBUCK + 1);
    const unsigned long long* kb = keys + (size_t)b * CAP;
    const unsigned long long* k2 = keys2 + (size_t)b * K2CAP;
    const unsigned long long* cd = cand + (size_t)b * CANDCAP;
    unsigned ccb = valid ? ccnt[b] : 0u;
    if (ccb > CANDCAP) ccb = CANDCAP;
    const float* pb = pred + (size_t)b * BATCH_FLOATS;
    float* ob = out + (size_t)b * MAXDET * 6;

    if (valid) for (int i = tid; i < NBUCK + 1; i += 1024) sgsL[i] = g2[i];
    if (tid == 0) s_nk = 0;
    __syncthreads();

#define GSV(v) (valid ? sgsL[(v) - PREBIN] : gs[(v)])

    unsigned limit;
    if (needv == 0x7FFFFFFF) limit = total;
    else limit = GSV(cutbin + 1) + (unsigned)needv;
    if (limit > total) limit = total;

    unsigned p = 0;
    while (p < limit) {
        if (s_nk >= MAXDET) break;

        // vs = smallest v with GSV(v) <= p + SORTCAP  -> maximal whole-bin extent
        int lo = cutbin, hi = NBIN - 1, vs = NBIN - 1;
        while (lo <= hi) { int mid = (lo + hi) >> 1;
            if (GSV(mid) <= p + (unsigned)SORTCAP) { vs = mid; hi = mid - 1; } else lo = mid + 1; }
        unsigned gEnd = GSV(vs);
        bool phaseA = (!valid) || (p < E);
        if (valid && phaseA && gEnd > E) gEnd = E;
        if (gEnd > total) gEnd = total;
        if (gEnd <= p) { gEnd = p + (unsigned)SORTCAP; if (gEnd > total) gEnd = total; }  // defensive
        unsigned G = gEnd - p;

        if (phaseA) {
            // dense bin-partitioned source indexed by absolute rank
            const unsigned long long* src = valid ? k2 : kb;
            unsigned myLo = 0, myHi = 0;
            unsigned long long raw = 0ULL;
            if (tid < (int)G) {
                unsigned idx = p + (unsigned)tid;
                int l2 = cutbin, h2 = NBIN - 1, v = cutbin;
                while (l2 <= h2) { int mid = (l2 + h2) >> 1;
                    if (GSV(mid) > idx) { v = mid; l2 = mid + 1; } else h2 = mid - 1; }
                unsigned bstart = GSV(v + 1);
                unsigned bend = GSV(v);
                raw = src[idx];
                myLo = (bstart > p) ? (bstart - p) : 0u;
                myHi = bend - p; if (myHi > G) myHi = G;
                ktmp[tid] = raw;
            }
            __syncthreads();
            if (tid < (int)G) {
                unsigned rank = 0;
                for (unsigned u = myLo; u < myHi; ++u) rank += (ktmp[u] > raw) ? 1u : 0u;
                skeys[myLo + rank] = raw;
            }
            __syncthreads();
        } else {
            // phase B (rare): filter-scan dense array for bins [vs, w1]
            int l0 = cutbin, h0 = NBIN - 1, w1 = cutbin;
            while (l0 <= h0) { int mid = (l0 + h0) >> 1;
                if (GSV(mid) > p) { w1 = mid; l0 = mid + 1; } else h0 = mid - 1; }
            if (tid == 0) s_gc = 0u;
            __syncthreads();
            for (unsigned k = tid; k < ccb; k += 1024) {
                unsigned long long key = cd[k];
                unsigned v = bin_of_bits((unsigned)(key >> 32));
                if ((int)v >= vs && (int)v <= w1) {
                    unsigned u = atomicAdd(&s_gc, 1u);
                    if (u < (unsigned)SORTCAP) ktmp[u] = key;
                }
            }
            __syncthreads();
            unsigned Gc = s_gc; if (Gc > (unsigned)SORTCAP) Gc = (unsigned)SORTCAP;
            if (tid < (int)Gc) {
                unsigned long long key = ktmp[tid];
                unsigned v = bin_of_bits((unsigned)(key >> 32));
                unsigned bstart = GSV(v + 1);
                unsigned rank = 0;
                for (unsigned u = 0; u < Gc; ++u) {
                    unsigned long long kk = ktmp[u];
                    unsigned vu = bin_of_bits((unsigned)(kk >> 32));
                    rank += (vu == v && kk > key) ? 1u : 0u;
                }
                skeys[(bstart - p) + rank] = key;
            }
            __syncthreads();
        }

        unsigned consumable = limit - p; if (consumable > G) consumable = G;

        for (unsigned c0 = 0; c0 < consumable; c0 += CH_SZ) {
            int nk0 = s_nk;
            if (nk0 >= MAXDET) break;
            int CH = (int)((consumable - c0 < (unsigned)CH_SZ) ? (consumable - c0) : (unsigned)CH_SZ);

            if (tid < CH_SZ * 4) rowMW[tid >> 2][tid & 3] = 0u;
            if (tid >= CH_SZ * 4 && tid < CH_SZ * 4 + 4) sup0w[tid - CH_SZ * 4] = 0u;
            if (tid < CH) {
                unsigned long long kk = skeys[c0 + tid];
                unsigned flat = 0xFFFFFFFFu - (unsigned)kk;
                unsigned bi = flat / (unsigned)NCLS;
                unsigned cc = flat - bi * (unsigned)NCLS;
                const float* rp = pb + (size_t)bi * ROWF;
                float cx = rp[0], cy = rp[1], wd = rp[2], ht = rp[3];
                float hw = __fmul_rn(0.5f, wd), hh = __fmul_rn(0.5f, ht);
                float off = __fmul_rn((float)cc, 4096.0f);
                float x1 = __fsub_rn(cx, hw), y1 = __fsub_rn(cy, hh);
                float x2 = __fadd_rn(cx, hw), y2 = __fadd_rn(cy, hh);
                float ox1 = __fadd_rn(x1, off), oy1 = __fadd_rn(y1, off);
                float ox2 = __fadd_rn(x2, off), oy2 = __fadd_rn(y2, off);
                cbox[tid][0] = ox1; cbox[tid][1] = oy1;
                cbox[tid][2] = ox2; cbox[tid][3] = oy2;
                cbox[tid][4] = __fmul_rn(__fsub_rn(ox2, ox1), __fsub_rn(oy2, oy1));
            }
            __syncthreads();

            {
                int col = tid & (CH_SZ - 1);
                int part = tid >> 7;
                if (col < CH) {
                    float bx1 = cbox[col][0], by1 = cbox[col][1];
                    float bx2 = cbox[col][2], by2 = cbox[col][3], ba = cbox[col][4];
                    unsigned part16 = 0u;
                    int rbase = part << 4;
                    for (int k = 0; k < 16; ++k) {
                        int i2 = rbase + k;
                        if (i2 >= col || i2 >= CH) break;
                        if (iou_gt_half(cbox[i2][0], cbox[i2][1], cbox[i2][2], cbox[i2][3],
                                        cbox[i2][4], bx1, by1, bx2, by2, ba))
                            part16 |= (1u << k);
                    }
                    // transpose-write: suppressing pairs are rare -> few atomics
                    while (part16) {
                        int k = __builtin_ctz(part16); part16 &= part16 - 1;
                        atomicOr(&rowMW[rbase + k][col >> 5], 1u << (col & 31));
                    }
                    bool f = false;
                    for (int k2 = part; k2 < nk0; k2 += 8) {
                        if (iou_gt_half(kept[k2][0], kept[k2][1], kept[k2][2], kept[k2][3],
                                        kept[k2][4], bx1, by1, bx2, by2, ba)) f = true;
                    }
                    if (f) atomicOr(&sup0w[col >> 5], 1u << (col & 31));
                }
            }
            __syncthreads();

            if (wv == 0) {
                // preload all row masks into lane registers: lane L holds rows L, L+64
                const unsigned long long* rmw = (const unsigned long long*)rowMW;
                unsigned long long rAlo = rmw[2 * lane];
                unsigned long long rAhi = rmw[2 * lane + 1];
                unsigned long long rBlo = rmw[2 * (lane + 64)];
                unsigned long long rBhi = rmw[2 * (lane + 64) + 1];
                unsigned long long S_lo = (unsigned long long)sup0w[0] |
                                          ((unsigned long long)sup0w[1] << 32);
                unsigned long long S_hi = (unsigned long long)sup0w[2] |
                                          ((unsigned long long)sup0w[3] << 32);
                int nkv = nk0, lk = 0;
                for (int j = 0; j < CH && nkv < MAXDET; ++j) {
                    bool sup = (j < 64) ? ((S_lo >> j) & 1ULL) : ((S_hi >> (j - 64)) & 1ULL);
                    if (!sup) {
                        int srcl = j & 63;
                        unsigned long long mlo, mhi;
                        if (j < 64) { mlo = readlane_u64(rAlo, srcl); mhi = readlane_u64(rAhi, srcl); }
                        else        { mlo = readlane_u64(rBlo, srcl); mhi = readlane_u64(rBhi, srcl); }
                        S_lo |= mlo; S_hi |= mhi;
                        if (lane == 0) klist[lk] = j;
                        ++lk; ++nkv;
                    }
                }
                if (lane == 0) { s_localk = lk; s_nk = nkv; }
            }
            __syncthreads();

            int lk = s_localk;
            for (int t2 = tid; t2 < lk; t2 += 1024) {
                int i = klist[t2];
                int oidx = nk0 + t2;
                kept[oidx][0] = cbox[i][0]; kept[oidx][1] = cbox[i][1];
                kept[oidx][2] = cbox[i][2]; kept[oidx][3] = cbox[i][3];
                kept[oidx][4] = cbox[i][4];
                unsigned long long kk = skeys[c0 + i];
                unsigned bits = (unsigned)(kk >> 32);
                unsigned flat = 0xFFFFFFFFu - (unsigned)kk;
                unsigned bi = flat / (unsigned)NCLS;
                unsigned cc = flat - bi * (unsigned)NCLS;
                const float* rp = pb + (size_t)bi * ROWF;
                float cx = rp[0], cy = rp[1], wd = rp[2], ht = rp[3];
                float hw = __fmul_rn(0.5f, wd), hh = __fmul_rn(0.5f, ht);
                float* orow = ob + (size_t)oidx * 6;
                orow[0] = __fsub_rn(cx, hw);
                orow[1] = __fsub_rn(cy, hh);
                orow[2] = __fadd_rn(cx, hw);
                orow[3] = __fadd_rn(cy, hh);
                orow[4] = __uint_as_float(bits);
                orow[5] = (float)cc;
            }
            __syncthreads();
        }
        p = gEnd;
    }
#undef GSV
}

// ---------------- launch --------------------------------------------------------------
extern "C" void kernel_launch(void* const* d_in, const int* in_sizes, int n_in,
                              void* d_out, int out_size, void* d_ws, size_t ws_size,
                              hipStream_t stream) {
    const float* pred = (const float*)d_in[0];
    float* outp = (float*)d_out;
    char* ws = (char*)d_ws;

    // zeroed region (contiguous)
    const size_t OFF_HIST  = 0;
    const size_t SZ_HIST   = (size_t)BATCH * NBIN * 4;               // 196,608
    const size_t OFF_CUR   = OFF_HIST + SZ_HIST;
    const size_t SZ_CUR    = (size_t)BATCH * NBIN * 4;               // 196,608
    const size_t OFF_H2    = OFF_CUR + SZ_CUR;
    const size_t SZ_H2     = (size_t)BATCH * NBUCK * 4;              // 65,536
    const size_t OFF_CCNT  = OFF_H2 + SZ_H2;
    const size_t SZ_CCNT   = (size_t)BATCH * 4;
    const size_t OFF_OFLW  = OFF_CCNT + SZ_CCNT;
    const size_t SZ_OFLW   = (size_t)BATCH * 4;
    const size_t OFF_META  = OFF_OFLW + SZ_OFLW;
    const size_t SZ_META   = (size_t)BATCH * 8 * 4;
    const size_t ZERO_SZ   = OFF_META + SZ_META;
    // non-zeroed
    const size_t OFF_SUF   = ZERO_SZ;
    const size_t SZ_SUF    = (size_t)BATCH * (NBIN + 1) * 4;
    const size_t OFF_SUF2  = OFF_SUF + SZ_SUF;
    const size_t SZ_SUF2   = (size_t)BATCH * (NBUCK + 1) * 4;
    const size_t OFF_KEYS  = OFF_SUF2 + SZ_SUF2;
    const size_t SZ_KEYS   = (size_t)BATCH * CAP * 8;                // 4,194,304
    const size_t OFF_K2    = OFF_KEYS + SZ_KEYS;
    const size_t SZ_K2     = (size_t)BATCH * K2CAP * 8;              // 524,288
    const size_t OFF_CAND  = OFF_K2 + SZ_K2;
    const size_t SZ_CAND   = (size_t)BATCH * CANDCAP * 8;            // 16,777,216
    const size_t WS_NEEDED = OFF_CAND + SZ_CAND;                     // ~22.4 MB

    int staged = (ws_size >= WS_NEEDED) ? 1 : 0;

    unsigned* hist             = (unsigned*)(ws + OFF_HIST);
    unsigned* cursor           = (unsigned*)(ws + OFF_CUR);
    unsigned* hist2            = (unsigned*)(ws + OFF_H2);
    unsigned* ccnt             = (unsigned*)(ws + OFF_CCNT);
    unsigned* oflow            = (unsigned*)(ws + OFF_OFLW);
    int* meta                  = (int*)(ws + OFF_META);
    unsigned* suf              = (unsigned*)(ws + OFF_SUF);
    unsigned* suf2             = (unsigned*)(ws + OFF_SUF2);
    unsigned long long* keys   = (unsigned long long*)(ws + OFF_KEYS);
    unsigned long long* keys2  = (unsigned long long*)(ws + OFF_K2);
    unsigned long long* cand   = (unsigned long long*)(ws + OFF_CAND);

    hipMemsetAsync(ws, 0, ZERO_SZ, stream);
    hipMemsetAsync(d_out, 0, (size_t)out_size * sizeof(float), stream);

    k_stage<<<dim3(BATCH * SBLK2), dim3(512), 0, stream>>>(pred, hist2, ccnt, cand, oflow, staged);
    k_prep<<<dim3(BATCH), dim3(1024), 0, stream>>>(hist2, ccnt, oflow, cand, suf2, keys2, meta, staged);
    k_hist_fb<<<dim3(BATCH * SBLK), dim3(256), 0, stream>>>(pred, hist, meta);
    k_scan_fb<<<dim3(BATCH), dim3(256), 0, stream>>>(hist, suf, meta);
    k_scatter_fb<<<dim3(BATCH * SBLK), dim3(256), 0, stream>>>(pred, suf, meta, cursor, keys);
    k_nms<<<dim3(BATCH), dim3(1024), 0, stream>>>(pred, suf, suf2, meta, ccnt, keys, keys2, cand, outp);
}